// Round 1
// baseline (576.591 us; speedup 1.0000x reference)
//
#include <hip/hip_runtime.h>
#include <cstddef>
#include <cstdint>

// Problem constants (fixed by the reference)
#define NN 50000      // nodes
#define EE 800000     // edges (before self loops)
#define FIN 128
#define D1 256        // HEADS*HID
#define HID 64
#define HEADS 4
#define NG 512
#define FOUT 64
#define NEG_SLOPE 0.2f
#define CAP 96        // slots per node; deg ~ Poisson(16), P(deg>96) ~ 1e-40

// h layout is SLICE-MAJOR: h[slice][n][32ch], slice = channel>>5.
// Rationale: slice k (3.2 MB) fits one XCD's 4 MB L2; aggregate blocks pick
// slice = blockIdx&7 so round-robin XCD dispatch pins slice k to XCD k ->
// gather traffic (435 MB/dispatch) becomes L2 hits instead of 216 MB of
// fabric re-fetch (each XCD previously streamed the whole 25.6 MB table).

typedef _Float16 f16x8 __attribute__((ext_vector_type(8)));
typedef _Float16 f16x4 __attribute__((ext_vector_type(4)));
typedef float f32x4 __attribute__((ext_vector_type(4)));

__device__ __forceinline__ float leaky(float x) { return fmaxf(x, NEG_SLOPE * x); }

// ---------------------------------------------------------------------------
// Adjacency build: fixed-capacity slot array, u16 node ids (NN < 65536).
// ---------------------------------------------------------------------------
__global__ void k_scatter_direct(const int* __restrict__ ei, int* __restrict__ cnt,
                                 unsigned short* __restrict__ slot) {
    int i = blockIdx.x * 256 + threadIdx.x;
    if (i < EE) {
        int s = ei[i], d = ei[EE + i];
        int p = atomicAdd(&cnt[d], 1);
        if (p < CAP)
            __builtin_nontemporal_store((unsigned short)s, &slot[(size_t)d * CAP + p]);
    }
}

// ---------------------------------------------------------------------------
// Weight transposes: W[K][256] fp32 -> Wt[256][K] fp16, both layers, 1 kernel
// ---------------------------------------------------------------------------
__global__ void k_cvt_w(const float* __restrict__ W1, const float* __restrict__ W2,
                        _Float16* __restrict__ w1t, _Float16* __restrict__ w2t) {
    int idx = blockIdx.x * 256 + threadIdx.x;
    if (idx < 256 * FIN) {
        int n = idx / FIN, k = idx - n * FIN;
        w1t[idx] = (_Float16)W1[(size_t)k * 256 + n];
    } else if (idx < 256 * FIN + 256 * D1) {
        int j = idx - 256 * FIN;
        int n = j >> 8, k = j & 255;
        w2t[j] = (_Float16)W2[(size_t)k * 256 + n];
    }
}

// ---------------------------------------------------------------------------
// MFMA fp16 GEMM (NT) with FUSED attention logits epilogue.
// C written SLICE-MAJOR [8][NN][32]. Layer-2 A operand is slice-major f16
// (written by aggregate); layer-1 A is row-major fp32 (input x).
// a_s/a_d written HEAD-MAJOR [4][NN] (per-XCD 200 KB table in aggregate).
// ---------------------------------------------------------------------------
#define BM 128
#define BN 128
#define BK 64
#define LDK (BK + 4)

template <int K, typename AT>
__global__ __launch_bounds__(256) void k_gemm(const AT* __restrict__ A,
                                              const _Float16* __restrict__ Bt,
                                              _Float16* __restrict__ C,
                                              const float* __restrict__ att_s,
                                              const float* __restrict__ att_d,
                                              float* __restrict__ a_s,
                                              float* __restrict__ a_d) {
    __shared__ _Float16 As[BM][LDK];
    __shared__ _Float16 Bs[BN][LDK];
    const int tid = threadIdx.x;
    const int lane = tid & 63;
    const int wave = tid >> 6;            // 0..3
    const int wm = wave & 1, wn = wave >> 1;
    const int m0 = blockIdx.x * BM;
    const int n0 = blockIdx.y * BN;
    const int row_m = lane & 15, quad = lane >> 4;

    f32x4 acc[4][4];
#pragma unroll
    for (int mi = 0; mi < 4; ++mi)
#pragma unroll
        for (int ni = 0; ni < 4; ++ni)
#pragma unroll
            for (int r = 0; r < 4; ++r) acc[mi][ni][r] = 0.f;

    const int c8 = (tid & 7) * 8;          // f16 column offset within row
    const int rr = tid >> 3;               // 0..31

    for (int k0 = 0; k0 < K; k0 += BK) {
#pragma unroll
        for (int p = 0; p < 4; ++p) {
            int r = p * 32 + rr;
            int gr = m0 + r; gr = gr < NN ? gr : NN - 1;
            f16x8 o;
            if constexpr (sizeof(AT) == 4) {
                const float4 v0 = *(const float4*)((const float*)A + (size_t)gr * K + k0 + c8);
                const float4 v1 = *(const float4*)((const float*)A + (size_t)gr * K + k0 + c8 + 4);
                o[0] = (_Float16)v0.x; o[1] = (_Float16)v0.y;
                o[2] = (_Float16)v0.z; o[3] = (_Float16)v0.w;
                o[4] = (_Float16)v1.x; o[5] = (_Float16)v1.y;
                o[6] = (_Float16)v1.z; o[7] = (_Float16)v1.w;
            } else {
                // slice-major A: [slice][NN][32]
                const int kk = k0 + c8;
                o = *(const f16x8*)((const _Float16*)A +
                        (size_t)(kk >> 5) * ((size_t)NN * 32) +
                        (size_t)gr * 32 + (kk & 31));
            }
            *(f16x8*)(&As[r][c8]) = o;
        }
#pragma unroll
        for (int p = 0; p < 4; ++p) {
            int r = p * 32 + rr;
            f16x8 v = *(const f16x8*)(Bt + (size_t)(n0 + r) * K + k0 + c8);
            *(f16x8*)(&Bs[r][c8]) = v;
        }
        __syncthreads();
#pragma unroll
        for (int kc = 0; kc < BK; kc += 32) {
            f16x8 af[4], bf[4];
#pragma unroll
            for (int mi = 0; mi < 4; ++mi)
                af[mi] = *(const f16x8*)(&As[wm * 64 + mi * 16 + row_m][kc + quad * 8]);
#pragma unroll
            for (int ni = 0; ni < 4; ++ni)
                bf[ni] = *(const f16x8*)(&Bs[wn * 64 + ni * 16 + row_m][kc + quad * 8]);
            // swapped operands: D holds C^T fragment
#pragma unroll
            for (int mi = 0; mi < 4; ++mi)
#pragma unroll
                for (int ni = 0; ni < 4; ++ni)
                    acc[mi][ni] = __builtin_amdgcn_mfma_f32_16x16x32_f16(
                        bf[ni], af[mi], acc[mi][ni], 0, 0, 0);
        }
        __syncthreads();
    }
    // store C (slice-major): value(lane,reg) of acc[mi][ni] is channel
    //   c = n0 + wn*64 + ni*16 + quad*4 + reg of row m.
#pragma unroll
    for (int mi = 0; mi < 4; ++mi) {
        int m = m0 + wm * 64 + mi * 16 + row_m;
        if (m < NN) {
#pragma unroll
            for (int ni = 0; ni < 4; ++ni) {
                f16x4 o;
                o[0] = (_Float16)acc[mi][ni][0];
                o[1] = (_Float16)acc[mi][ni][1];
                o[2] = (_Float16)acc[mi][ni][2];
                o[3] = (_Float16)acc[mi][ni][3];
                const int c = n0 + wn * 64 + ni * 16 + quad * 4;
                *(f16x4*)(C + (size_t)(c >> 5) * ((size_t)NN * 32) +
                          (size_t)m * 32 + (c & 31)) = o;
            }
        }
    }
    // fused logits: this wave's 64-ch slice == head (2*by + wn)
    const int head = blockIdx.y * 2 + wn;
    const float* attsv = att_s + head * HID;
    const float* attdv = att_d + head * HID;
    float avs[4][4], avd[4][4];
#pragma unroll
    for (int ni = 0; ni < 4; ++ni)
#pragma unroll
        for (int r = 0; r < 4; ++r) {
            avs[ni][r] = attsv[ni * 16 + quad * 4 + r];
            avd[ni][r] = attdv[ni * 16 + quad * 4 + r];
        }
#pragma unroll
    for (int mi = 0; mi < 4; ++mi) {
        float ps = 0.f, pd = 0.f;
#pragma unroll
        for (int ni = 0; ni < 4; ++ni)
#pragma unroll
            for (int r = 0; r < 4; ++r) {
                ps += acc[mi][ni][r] * avs[ni][r];
                pd += acc[mi][ni][r] * avd[ni][r];
            }
        ps += __shfl_xor(ps, 16); ps += __shfl_xor(ps, 32);
        pd += __shfl_xor(pd, 16); pd += __shfl_xor(pd, 32);
        int m = m0 + wm * 64 + mi * 16 + row_m;
        if (quad == 0 && m < NN) {
            a_s[(size_t)head * NN + m] = ps;   // head-major
            a_d[(size_t)head * NN + m] = pd;
        }
    }
}

// ---------------------------------------------------------------------------
// Sliced GAT softmax + aggregation: one wave per (dst node, 32-ch slice).
// slice = blockIdx&7  -> round-robin dispatch pins slice k to XCD k; the
// slice's h region (3.2 MB) stays L2-resident, so the random h[src] gathers
// (the 216 MB FETCH in the previous version) become L2 hits.
// 8 edges / iteration: group g = lane>>3 owns edge base+g, its 8 lanes hold
// f16x4 channels. Weights recomputed per slice (a_s head-major, 200 KB/XCD).
// No LDS, no barriers; butterfly shfl reduce over the 8 groups at the end.
// 4 waves (4 consecutive dst nodes) per 256-thr block.
// ---------------------------------------------------------------------------
__global__ __launch_bounds__(256) void k_aggregate(
    const _Float16* __restrict__ h, const float* __restrict__ a_s,
    const float* __restrict__ a_d, const int* __restrict__ cnt,
    const unsigned short* __restrict__ slot, const float* __restrict__ bias,
    _Float16* __restrict__ out, int apply_elu) {
    const int tid = threadIdx.x;
    const int wv = __builtin_amdgcn_readfirstlane(tid >> 6);   // wave 0..3
    const int lane = tid & 63;
    const int slice = blockIdx.x & 7;
    const int n = ((blockIdx.x >> 3) << 2) + wv;
    const int head = slice >> 1;
    const int g = lane >> 3;              // edge group 0..7
    const int ch = (lane & 7) * 4;        // channel offset within slice

    const _Float16* __restrict__ hs = h + (size_t)slice * ((size_t)NN * 32);
    const float* __restrict__ asv = a_s + (size_t)head * NN;
    const float adn = a_d[(size_t)head * NN + n];
    const int deg = min(cnt[n], CAP);
    const unsigned short* __restrict__ sl = slot + (size_t)n * CAP;

    float acc0 = 0.f, acc1 = 0.f, acc2 = 0.f, acc3 = 0.f, l = 0.f;

#pragma unroll 2
    for (int base = 0; base < deg; base += 8) {
        const int j = base + g;
        const bool act = j < deg;
        int s = sl[act ? j : 0];          // clamped addr: never OOB
        s = act ? s : n;                  // force valid row (junk may be NaN)
        const float t = asv[s] + adn;
        const float w = act ? __expf(leaky(t)) : 0.f;
        const f16x4 hv = *(const f16x4*)(hs + ((size_t)s << 5) + ch);
        l += w;
        acc0 += w * (float)hv[0];
        acc1 += w * (float)hv[1];
        acc2 += w * (float)hv[2];
        acc3 += w * (float)hv[3];
    }
    // reduce across the 8 edge groups (lane bits 3,4,5)
    acc0 += __shfl_xor(acc0, 8); acc0 += __shfl_xor(acc0, 16); acc0 += __shfl_xor(acc0, 32);
    acc1 += __shfl_xor(acc1, 8); acc1 += __shfl_xor(acc1, 16); acc1 += __shfl_xor(acc1, 32);
    acc2 += __shfl_xor(acc2, 8); acc2 += __shfl_xor(acc2, 16); acc2 += __shfl_xor(acc2, 32);
    acc3 += __shfl_xor(acc3, 8); acc3 += __shfl_xor(acc3, 16); acc3 += __shfl_xor(acc3, 32);
    l    += __shfl_xor(l, 8);    l    += __shfl_xor(l, 16);    l    += __shfl_xor(l, 32);

    // self loop (every lane holds the full per-channel sums after butterfly)
    const float ts = asv[n] + adn;
    const float ws = __expf(leaky(ts));
    const f16x4 hn = *(const f16x4*)(hs + ((size_t)n << 5) + ch);
    l += ws;
    acc0 += ws * (float)hn[0];
    acc1 += ws * (float)hn[1];
    acc2 += ws * (float)hn[2];
    acc3 += ws * (float)hn[3];

    const float inv = 1.f / l;
    const float4 bb = *(const float4*)(bias + (slice << 5) + ch);
    float v0 = acc0 * inv + bb.x;
    float v1 = acc1 * inv + bb.y;
    float v2 = acc2 * inv + bb.z;
    float v3 = acc3 * inv + bb.w;
    if (apply_elu) {
        v0 = v0 > 0.f ? v0 : expm1f(v0);
        v1 = v1 > 0.f ? v1 : expm1f(v1);
        v2 = v2 > 0.f ? v2 : expm1f(v2);
        v3 = v3 > 0.f ? v3 : expm1f(v3);
    }
    if (lane < 8) {
        f16x4 o;
        o[0] = (_Float16)v0; o[1] = (_Float16)v1;
        o[2] = (_Float16)v2; o[3] = (_Float16)v3;
        *(f16x4*)(out + (size_t)slice * ((size_t)NN * 32) + ((size_t)n << 5) + ch) = o;
    }
}

// ---------------------------------------------------------------------------
// Fused global mean pool + final FC: one 256-thr block per graph.
// h is slice-major: channel c of node n at h[(c>>5)*NN*32 + n*32 + (c&31)].
// ---------------------------------------------------------------------------
__global__ __launch_bounds__(256) void k_pool_fc(const _Float16* __restrict__ h,
                                                 const int* __restrict__ batch,
                                                 const float* __restrict__ fc_w,
                                                 const float* __restrict__ fc_b,
                                                 float* __restrict__ out) {
    __shared__ float row[D1];
    int g = blockIdx.x, c = threadIdx.x;
    int lo = 0, hi = NN;
    while (lo < hi) { int mid = (lo + hi) >> 1; if (batch[mid] < g) lo = mid + 1; else hi = mid; }
    int start = lo;
    hi = NN;
    while (lo < hi) { int mid = (lo + hi) >> 1; if (batch[mid] < g + 1) lo = mid + 1; else hi = mid; }
    int end = lo;

    const _Float16* hsl = h + (size_t)(c >> 5) * ((size_t)NN * 32) + (c & 31);
    float acc = 0.f;
    for (int n = start; n < end; ++n) acc += (float)hsl[(size_t)n << 5];
    float inv = 1.f / fmaxf((float)(end - start), 1.f);
    row[c] = acc * inv;
    __syncthreads();
    if (c < FOUT) {
        float o = 0.f;
#pragma unroll 4
        for (int k = 0; k < D1; ++k) o += row[k] * fc_w[k * FOUT + c];
        out[(size_t)g * FOUT + c] = o + fc_b[c];
    }
}

// ---------------------------------------------------------------------------
extern "C" void kernel_launch(void* const* d_in, const int* in_sizes, int n_in,
                              void* d_out, int out_size, void* d_ws, size_t ws_size,
                              hipStream_t stream) {
    const float* x        = (const float*)d_in[0];
    const int*   ei       = (const int*)d_in[1];
    const int*   batch    = (const int*)d_in[2];
    const float* W1       = (const float*)d_in[3];
    const float* att_src1 = (const float*)d_in[4];
    const float* att_dst1 = (const float*)d_in[5];
    const float* b1       = (const float*)d_in[6];
    const float* W2       = (const float*)d_in[7];
    const float* att_src2 = (const float*)d_in[8];
    const float* att_dst2 = (const float*)d_in[9];
    const float* b2       = (const float*)d_in[10];
    const float* fc_w     = (const float*)d_in[11];
    const float* fc_b     = (const float*)d_in[12];
    float* out = (float*)d_out;

    // workspace carve-up (~63 MB)
    _Float16* h_pre  = (_Float16*)d_ws;                       // NN*D1 f16 (slice-major)
    _Float16* h_act  = h_pre + (size_t)NN * D1;               // NN*D1 f16 (slice-major)
    _Float16* w1t    = h_act + (size_t)NN * D1;               // 256*128
    _Float16* w2t    = w1t + 256 * FIN;                       // 256*256
    float* a_s       = (float*)(w2t + 256 * D1);              // [4][NN] head-major
    float* a_d       = a_s + (size_t)NN * 4;
    int*   cnt       = (int*)(a_d + (size_t)NN * 4);          // NN ints
    unsigned short* slot16 = (unsigned short*)(cnt + NN);     // NN*CAP u16 (9.6 MB)

    const int nblk_edges = (EE + 255) / 256;

    // ---- adjacency build (memset + single scatter; scan-free) ----
    hipMemsetAsync(cnt, 0, NN * sizeof(int), stream);
    k_scatter_direct<<<nblk_edges, 256, 0, stream>>>(ei, cnt, slot16);

    // ---- weight transposes (1 dispatch) ----
    k_cvt_w<<<(256 * (FIN + D1) + 255) / 256, 256, 0, stream>>>(W1, W2, w1t, w2t);

    dim3 ggrid((NN + BM - 1) / BM, D1 / BN);
    const int agg_grid = (NN / 4) * 8;   // 4 nodes/block x 8 slices

    // ---- layer 1 (GEMM + fused logits, sliced aggregate) ----
    k_gemm<FIN, float><<<ggrid, 256, 0, stream>>>(x, w1t, h_pre,
                                                  att_src1, att_dst1, a_s, a_d);
    k_aggregate<<<agg_grid, 256, 0, stream>>>(h_pre, a_s, a_d, cnt, slot16, b1, h_act, 1);

    // ---- layer 2 ----
    k_gemm<D1, _Float16><<<ggrid, 256, 0, stream>>>(h_act, w2t, h_pre,
                                                    att_src2, att_dst2, a_s, a_d);
    k_aggregate<<<agg_grid, 256, 0, stream>>>(h_pre, a_s, a_d, cnt, slot16, b2, h_act, 1);

    // ---- fused pool + fc ----
    k_pool_fc<<<NG, 256, 0, stream>>>(h_act, batch, fc_w, fc_b, out);
}

// Round 2
// 478.403 us; speedup vs baseline: 1.2052x; 1.2052x over previous
//
#include <hip/hip_runtime.h>
#include <cstddef>
#include <cstdint>

// Problem constants (fixed by the reference)
#define NN 50000      // nodes
#define EE 800000     // edges (before self loops)
#define FIN 128
#define D1 256        // HEADS*HID
#define HID 64
#define HEADS 4
#define NG 512
#define FOUT 64
#define NEG_SLOPE 0.2f
#define CAP 96        // slots per node; deg ~ Poisson(16), P(deg>96) ~ 1e-40

// h layout is SLICE-MAJOR: h[slice][n][32ch], slice = channel>>5.
// slice k (3.2 MB) fits one XCD's 4 MB L2; aggregate blocks pick
// slice = blockIdx&7 so round-robin XCD dispatch pins slice k to XCD k.
// R1 PROVED the residency (FETCH 216->60 MB) but was issue-bound on per-wave
// overhead (400k waves x 15 shfl + expm1f epilogue). R2: group=NODE not edge,
// serial edges, zero shuffles, 8 nodes/wave, expf-1 ELU.

typedef _Float16 f16x8 __attribute__((ext_vector_type(8)));
typedef _Float16 f16x4 __attribute__((ext_vector_type(4)));
typedef float f32x4 __attribute__((ext_vector_type(4)));

__device__ __forceinline__ float leaky(float x) { return fmaxf(x, NEG_SLOPE * x); }

// ---------------------------------------------------------------------------
// Adjacency build: fixed-capacity slot array, u16 node ids (NN < 65536).
// ---------------------------------------------------------------------------
__global__ void k_scatter_direct(const int* __restrict__ ei, int* __restrict__ cnt,
                                 unsigned short* __restrict__ slot) {
    int i = blockIdx.x * 256 + threadIdx.x;
    if (i < EE) {
        int s = ei[i], d = ei[EE + i];
        int p = atomicAdd(&cnt[d], 1);
        if (p < CAP)
            __builtin_nontemporal_store((unsigned short)s, &slot[(size_t)d * CAP + p]);
    }
}

// ---------------------------------------------------------------------------
// Weight transposes: W[K][256] fp32 -> Wt[256][K] fp16, both layers, 1 kernel
// ---------------------------------------------------------------------------
__global__ void k_cvt_w(const float* __restrict__ W1, const float* __restrict__ W2,
                        _Float16* __restrict__ w1t, _Float16* __restrict__ w2t) {
    int idx = blockIdx.x * 256 + threadIdx.x;
    if (idx < 256 * FIN) {
        int n = idx / FIN, k = idx - n * FIN;
        w1t[idx] = (_Float16)W1[(size_t)k * 256 + n];
    } else if (idx < 256 * FIN + 256 * D1) {
        int j = idx - 256 * FIN;
        int n = j >> 8, k = j & 255;
        w2t[j] = (_Float16)W2[(size_t)k * 256 + n];
    }
}

// ---------------------------------------------------------------------------
// MFMA fp16 GEMM (NT) with FUSED attention logits epilogue.
// C written SLICE-MAJOR [8][NN][32]. Layer-2 A operand is slice-major f16;
// layer-1 A is row-major fp32 (input x). a_s/a_d written HEAD-MAJOR [4][NN].
// ---------------------------------------------------------------------------
#define BM 128
#define BN 128
#define BK 64
#define LDK (BK + 4)

template <int K, typename AT>
__global__ __launch_bounds__(256) void k_gemm(const AT* __restrict__ A,
                                              const _Float16* __restrict__ Bt,
                                              _Float16* __restrict__ C,
                                              const float* __restrict__ att_s,
                                              const float* __restrict__ att_d,
                                              float* __restrict__ a_s,
                                              float* __restrict__ a_d) {
    __shared__ _Float16 As[BM][LDK];
    __shared__ _Float16 Bs[BN][LDK];
    const int tid = threadIdx.x;
    const int lane = tid & 63;
    const int wave = tid >> 6;            // 0..3
    const int wm = wave & 1, wn = wave >> 1;
    const int m0 = blockIdx.x * BM;
    const int n0 = blockIdx.y * BN;
    const int row_m = lane & 15, quad = lane >> 4;

    f32x4 acc[4][4];
#pragma unroll
    for (int mi = 0; mi < 4; ++mi)
#pragma unroll
        for (int ni = 0; ni < 4; ++ni)
#pragma unroll
            for (int r = 0; r < 4; ++r) acc[mi][ni][r] = 0.f;

    const int c8 = (tid & 7) * 8;          // f16 column offset within row
    const int rr = tid >> 3;               // 0..31

    for (int k0 = 0; k0 < K; k0 += BK) {
#pragma unroll
        for (int p = 0; p < 4; ++p) {
            int r = p * 32 + rr;
            int gr = m0 + r; gr = gr < NN ? gr : NN - 1;
            f16x8 o;
            if constexpr (sizeof(AT) == 4) {
                const float4 v0 = *(const float4*)((const float*)A + (size_t)gr * K + k0 + c8);
                const float4 v1 = *(const float4*)((const float*)A + (size_t)gr * K + k0 + c8 + 4);
                o[0] = (_Float16)v0.x; o[1] = (_Float16)v0.y;
                o[2] = (_Float16)v0.z; o[3] = (_Float16)v0.w;
                o[4] = (_Float16)v1.x; o[5] = (_Float16)v1.y;
                o[6] = (_Float16)v1.z; o[7] = (_Float16)v1.w;
            } else {
                // slice-major A: [slice][NN][32]
                const int kk = k0 + c8;
                o = *(const f16x8*)((const _Float16*)A +
                        (size_t)(kk >> 5) * ((size_t)NN * 32) +
                        (size_t)gr * 32 + (kk & 31));
            }
            *(f16x8*)(&As[r][c8]) = o;
        }
#pragma unroll
        for (int p = 0; p < 4; ++p) {
            int r = p * 32 + rr;
            f16x8 v = *(const f16x8*)(Bt + (size_t)(n0 + r) * K + k0 + c8);
            *(f16x8*)(&Bs[r][c8]) = v;
        }
        __syncthreads();
#pragma unroll
        for (int kc = 0; kc < BK; kc += 32) {
            f16x8 af[4], bf[4];
#pragma unroll
            for (int mi = 0; mi < 4; ++mi)
                af[mi] = *(const f16x8*)(&As[wm * 64 + mi * 16 + row_m][kc + quad * 8]);
#pragma unroll
            for (int ni = 0; ni < 4; ++ni)
                bf[ni] = *(const f16x8*)(&Bs[wn * 64 + ni * 16 + row_m][kc + quad * 8]);
            // swapped operands: D holds C^T fragment
#pragma unroll
            for (int mi = 0; mi < 4; ++mi)
#pragma unroll
                for (int ni = 0; ni < 4; ++ni)
                    acc[mi][ni] = __builtin_amdgcn_mfma_f32_16x16x32_f16(
                        bf[ni], af[mi], acc[mi][ni], 0, 0, 0);
        }
        __syncthreads();
    }
    // store C (slice-major): value(lane,reg) of acc[mi][ni] is channel
    //   c = n0 + wn*64 + ni*16 + quad*4 + reg of row m.
#pragma unroll
    for (int mi = 0; mi < 4; ++mi) {
        int m = m0 + wm * 64 + mi * 16 + row_m;
        if (m < NN) {
#pragma unroll
            for (int ni = 0; ni < 4; ++ni) {
                f16x4 o;
                o[0] = (_Float16)acc[mi][ni][0];
                o[1] = (_Float16)acc[mi][ni][1];
                o[2] = (_Float16)acc[mi][ni][2];
                o[3] = (_Float16)acc[mi][ni][3];
                const int c = n0 + wn * 64 + ni * 16 + quad * 4;
                *(f16x4*)(C + (size_t)(c >> 5) * ((size_t)NN * 32) +
                          (size_t)m * 32 + (c & 31)) = o;
            }
        }
    }
    // fused logits: this wave's 64-ch slice == head (2*by + wn)
    const int head = blockIdx.y * 2 + wn;
    const float* attsv = att_s + head * HID;
    const float* attdv = att_d + head * HID;
    float avs[4][4], avd[4][4];
#pragma unroll
    for (int ni = 0; ni < 4; ++ni)
#pragma unroll
        for (int r = 0; r < 4; ++r) {
            avs[ni][r] = attsv[ni * 16 + quad * 4 + r];
            avd[ni][r] = attdv[ni * 16 + quad * 4 + r];
        }
#pragma unroll
    for (int mi = 0; mi < 4; ++mi) {
        float ps = 0.f, pd = 0.f;
#pragma unroll
        for (int ni = 0; ni < 4; ++ni)
#pragma unroll
            for (int r = 0; r < 4; ++r) {
                ps += acc[mi][ni][r] * avs[ni][r];
                pd += acc[mi][ni][r] * avd[ni][r];
            }
        ps += __shfl_xor(ps, 16); ps += __shfl_xor(ps, 32);
        pd += __shfl_xor(pd, 16); pd += __shfl_xor(pd, 32);
        int m = m0 + wm * 64 + mi * 16 + row_m;
        if (quad == 0 && m < NN) {
            a_s[(size_t)head * NN + m] = ps;   // head-major
            a_d[(size_t)head * NN + m] = pd;
        }
    }
}

// ---------------------------------------------------------------------------
// Sliced GAT softmax + aggregation, R2 structure:
//   slice = blockIdx&7 (XCD-pinned, L2-resident h slice: proven in R1).
//   Wave handles 8 dst nodes: group g = lane>>3 owns node n0+g; its 8 lanes
//   hold the node's 32 slice-channels (f16x4/lane). Edges run SERIALLY per
//   node, all groups in lockstep to the group-max degree. Each lane's acc is
//   final -> ZERO reduction shuffles. 32 nodes / 256-thr block.
// ---------------------------------------------------------------------------
__global__ __launch_bounds__(256) void k_aggregate(
    const _Float16* __restrict__ h, const float* __restrict__ a_s,
    const float* __restrict__ a_d, const int* __restrict__ cnt,
    const unsigned short* __restrict__ slot, const float* __restrict__ bias,
    _Float16* __restrict__ out, int apply_elu) {
    const int tid = threadIdx.x;
    const int lane = tid & 63;
    const int wv = tid >> 6;              // wave 0..3
    const int slice = blockIdx.x & 7;
    const int head = slice >> 1;
    const int g = lane >> 3;              // node sub-index 0..7
    const int ch = (lane & 7) * 4;        // channel offset within slice

    const int n = (blockIdx.x >> 3) * 32 + wv * 8 + g;
    const bool nvalid = n < NN;
    const int nc = nvalid ? n : NN - 1;

    const _Float16* __restrict__ hs = h + (size_t)slice * ((size_t)NN * 32);
    const float* __restrict__ asv = a_s + (size_t)head * NN;

    const int deg = nvalid ? min(cnt[nc], CAP) : 0;
    const float adn = a_d[(size_t)head * NN + nc];
    const unsigned short* __restrict__ sl = slot + (size_t)nc * CAP;

    // self-loop seed (each lane: full contribution for its 4 channels)
    const float ws = __expf(leaky(asv[nc] + adn));
    const f16x4 hn = *(const f16x4*)(hs + ((size_t)nc << 5) + ch);
    float l = ws;
    float acc0 = ws * (float)hn[0];
    float acc1 = ws * (float)hn[1];
    float acc2 = ws * (float)hn[2];
    float acc3 = ws * (float)hn[3];

    // wave-max degree across the 8 groups (one-time cost)
    int md = deg;
    md = max(md, __shfl_xor(md, 8));
    md = max(md, __shfl_xor(md, 16));
    md = max(md, __shfl_xor(md, 32));

#pragma unroll 4
    for (int j = 0; j < md; ++j) {
        const bool act = j < deg;
        int s = (int)sl[act ? j : 0];     // clamped addr: never OOB
        s = act ? s : nc;                 // junk slot may be garbage -> force valid
        const float w = act ? __expf(leaky(asv[s] + adn)) : 0.f;
        const f16x4 hv = *(const f16x4*)(hs + ((size_t)s << 5) + ch);
        l += w;
        acc0 += w * (float)hv[0];
        acc1 += w * (float)hv[1];
        acc2 += w * (float)hv[2];
        acc3 += w * (float)hv[3];
    }

    const float inv = 1.f / l;
    const float4 bb = *(const float4*)(bias + (slice << 5) + ch);
    float v0 = acc0 * inv + bb.x;
    float v1 = acc1 * inv + bb.y;
    float v2 = acc2 * inv + bb.z;
    float v3 = acc3 * inv + bb.w;
    if (apply_elu) {
        // expf-1 instead of expm1f: output is f16 (ulp 5e-4), error ~1e-7
        v0 = v0 > 0.f ? v0 : __expf(v0) - 1.f;
        v1 = v1 > 0.f ? v1 : __expf(v1) - 1.f;
        v2 = v2 > 0.f ? v2 : __expf(v2) - 1.f;
        v3 = v3 > 0.f ? v3 : __expf(v3) - 1.f;
    }
    if (nvalid) {
        f16x4 o;
        o[0] = (_Float16)v0; o[1] = (_Float16)v1;
        o[2] = (_Float16)v2; o[3] = (_Float16)v3;
        *(f16x4*)(out + (size_t)slice * ((size_t)NN * 32) + ((size_t)n << 5) + ch) = o;
    }
}

// ---------------------------------------------------------------------------
// Fused global mean pool + final FC: one 256-thr block per graph.
// h slice-major: channel c of node n at h[(c>>5)*NN*32 + n*32 + (c&31)].
// ---------------------------------------------------------------------------
__global__ __launch_bounds__(256) void k_pool_fc(const _Float16* __restrict__ h,
                                                 const int* __restrict__ batch,
                                                 const float* __restrict__ fc_w,
                                                 const float* __restrict__ fc_b,
                                                 float* __restrict__ out) {
    __shared__ float row[D1];
    int g = blockIdx.x, c = threadIdx.x;
    int lo = 0, hi = NN;
    while (lo < hi) { int mid = (lo + hi) >> 1; if (batch[mid] < g) lo = mid + 1; else hi = mid; }
    int start = lo;
    hi = NN;
    while (lo < hi) { int mid = (lo + hi) >> 1; if (batch[mid] < g + 1) lo = mid + 1; else hi = mid; }
    int end = lo;

    const _Float16* hsl = h + (size_t)(c >> 5) * ((size_t)NN * 32) + (c & 31);
    float acc = 0.f;
    for (int n = start; n < end; ++n) acc += (float)hsl[(size_t)n << 5];
    float inv = 1.f / fmaxf((float)(end - start), 1.f);
    row[c] = acc * inv;
    __syncthreads();
    if (c < FOUT) {
        float o = 0.f;
#pragma unroll 4
        for (int k = 0; k < D1; ++k) o += row[k] * fc_w[k * FOUT + c];
        out[(size_t)g * FOUT + c] = o + fc_b[c];
    }
}

// ---------------------------------------------------------------------------
extern "C" void kernel_launch(void* const* d_in, const int* in_sizes, int n_in,
                              void* d_out, int out_size, void* d_ws, size_t ws_size,
                              hipStream_t stream) {
    const float* x        = (const float*)d_in[0];
    const int*   ei       = (const int*)d_in[1];
    const int*   batch    = (const int*)d_in[2];
    const float* W1       = (const float*)d_in[3];
    const float* att_src1 = (const float*)d_in[4];
    const float* att_dst1 = (const float*)d_in[5];
    const float* b1       = (const float*)d_in[6];
    const float* W2       = (const float*)d_in[7];
    const float* att_src2 = (const float*)d_in[8];
    const float* att_dst2 = (const float*)d_in[9];
    const float* b2       = (const float*)d_in[10];
    const float* fc_w     = (const float*)d_in[11];
    const float* fc_b     = (const float*)d_in[12];
    float* out = (float*)d_out;

    // workspace carve-up (~63 MB)
    _Float16* h_pre  = (_Float16*)d_ws;                       // NN*D1 f16 (slice-major)
    _Float16* h_act  = h_pre + (size_t)NN * D1;               // NN*D1 f16 (slice-major)
    _Float16* w1t    = h_act + (size_t)NN * D1;               // 256*128
    _Float16* w2t    = w1t + 256 * FIN;                       // 256*256
    float* a_s       = (float*)(w2t + 256 * D1);              // [4][NN] head-major
    float* a_d       = a_s + (size_t)NN * 4;
    int*   cnt       = (int*)(a_d + (size_t)NN * 4);          // NN ints
    unsigned short* slot16 = (unsigned short*)(cnt + NN);     // NN*CAP u16 (9.6 MB)

    const int nblk_edges = (EE + 255) / 256;

    // ---- adjacency build (memset + single scatter; scan-free) ----
    hipMemsetAsync(cnt, 0, NN * sizeof(int), stream);
    k_scatter_direct<<<nblk_edges, 256, 0, stream>>>(ei, cnt, slot16);

    // ---- weight transposes (1 dispatch) ----
    k_cvt_w<<<(256 * (FIN + D1) + 255) / 256, 256, 0, stream>>>(W1, W2, w1t, w2t);

    dim3 ggrid((NN + BM - 1) / BM, D1 / BN);
    const int agg_grid = ((NN + 31) / 32) * 8;   // 32 nodes/block x 8 slices

    // ---- layer 1 (GEMM + fused logits, sliced aggregate) ----
    k_gemm<FIN, float><<<ggrid, 256, 0, stream>>>(x, w1t, h_pre,
                                                  att_src1, att_dst1, a_s, a_d);
    k_aggregate<<<agg_grid, 256, 0, stream>>>(h_pre, a_s, a_d, cnt, slot16, b1, h_act, 1);

    // ---- layer 2 ----
    k_gemm<D1, _Float16><<<ggrid, 256, 0, stream>>>(h_act, w2t, h_pre,
                                                    att_src2, att_dst2, a_s, a_d);
    k_aggregate<<<agg_grid, 256, 0, stream>>>(h_pre, a_s, a_d, cnt, slot16, b2, h_act, 1);

    // ---- fused pool + fc ----
    k_pool_fc<<<NG, 256, 0, stream>>>(h_act, batch, fc_w, fc_b, out);
}

// Round 3
// 408.961 us; speedup vs baseline: 1.4099x; 1.1698x over previous
//
#include <hip/hip_runtime.h>
#include <cstddef>
#include <cstdint>

// Problem constants (fixed by the reference)
#define NN 50000      // nodes
#define EE 800000     // edges (before self loops)
#define FIN 128
#define D1 256        // HEADS*HID
#define HID 64
#define HEADS 4
#define NG 512
#define FOUT 64
#define NEG_SLOPE 0.2f
#define CAP 96        // slots per node; deg ~ Poisson(16), P(deg>96) ~ 1e-40

// h layout is SLICE-MAJOR: h[slice][n][32ch], slice = channel>>5.
// slice k (3.2 MB) fits one XCD's 4 MB L2; aggregate blocks pick
// slice = blockIdx&7 so round-robin XCD dispatch pins slice k to XCD k.
// R1 proved residency (FETCH 216->60 MB). R2 (group=node, serial edges) was
// LATENCY-bound: slot->gather dependent chain, VALUBusy 39%. R3: batched
// u16x8 slot prefetch (software-pipelined) + unroll-8 gathers -> 16 loads in
// flight per lane, slot latency hidden.

typedef _Float16 f16x8 __attribute__((ext_vector_type(8)));
typedef _Float16 f16x4 __attribute__((ext_vector_type(4)));
typedef float f32x4 __attribute__((ext_vector_type(4)));
typedef unsigned short u16x8 __attribute__((ext_vector_type(8)));

__device__ __forceinline__ float leaky(float x) { return fmaxf(x, NEG_SLOPE * x); }

// ---------------------------------------------------------------------------
// Adjacency build: fixed-capacity slot array, u16 node ids (NN < 65536).
// ---------------------------------------------------------------------------
__global__ void k_scatter_direct(const int* __restrict__ ei, int* __restrict__ cnt,
                                 unsigned short* __restrict__ slot) {
    int i = blockIdx.x * 256 + threadIdx.x;
    if (i < EE) {
        int s = ei[i], d = ei[EE + i];
        int p = atomicAdd(&cnt[d], 1);
        if (p < CAP)
            __builtin_nontemporal_store((unsigned short)s, &slot[(size_t)d * CAP + p]);
    }
}

// ---------------------------------------------------------------------------
// Weight transposes: W[K][256] fp32 -> Wt[256][K] fp16, both layers, 1 kernel
// ---------------------------------------------------------------------------
__global__ void k_cvt_w(const float* __restrict__ W1, const float* __restrict__ W2,
                        _Float16* __restrict__ w1t, _Float16* __restrict__ w2t) {
    int idx = blockIdx.x * 256 + threadIdx.x;
    if (idx < 256 * FIN) {
        int n = idx / FIN, k = idx - n * FIN;
        w1t[idx] = (_Float16)W1[(size_t)k * 256 + n];
    } else if (idx < 256 * FIN + 256 * D1) {
        int j = idx - 256 * FIN;
        int n = j >> 8, k = j & 255;
        w2t[j] = (_Float16)W2[(size_t)k * 256 + n];
    }
}

// ---------------------------------------------------------------------------
// MFMA fp16 GEMM (NT) with FUSED attention logits epilogue.
// C written SLICE-MAJOR [8][NN][32]. Layer-2 A operand is slice-major f16;
// layer-1 A is row-major fp32 (input x). a_s/a_d written HEAD-MAJOR [4][NN].
// ---------------------------------------------------------------------------
#define BM 128
#define BN 128
#define BK 64
#define LDK (BK + 4)

template <int K, typename AT>
__global__ __launch_bounds__(256) void k_gemm(const AT* __restrict__ A,
                                              const _Float16* __restrict__ Bt,
                                              _Float16* __restrict__ C,
                                              const float* __restrict__ att_s,
                                              const float* __restrict__ att_d,
                                              float* __restrict__ a_s,
                                              float* __restrict__ a_d) {
    __shared__ _Float16 As[BM][LDK];
    __shared__ _Float16 Bs[BN][LDK];
    const int tid = threadIdx.x;
    const int lane = tid & 63;
    const int wave = tid >> 6;            // 0..3
    const int wm = wave & 1, wn = wave >> 1;
    const int m0 = blockIdx.x * BM;
    const int n0 = blockIdx.y * BN;
    const int row_m = lane & 15, quad = lane >> 4;

    f32x4 acc[4][4];
#pragma unroll
    for (int mi = 0; mi < 4; ++mi)
#pragma unroll
        for (int ni = 0; ni < 4; ++ni)
#pragma unroll
            for (int r = 0; r < 4; ++r) acc[mi][ni][r] = 0.f;

    const int c8 = (tid & 7) * 8;          // f16 column offset within row
    const int rr = tid >> 3;               // 0..31

    for (int k0 = 0; k0 < K; k0 += BK) {
#pragma unroll
        for (int p = 0; p < 4; ++p) {
            int r = p * 32 + rr;
            int gr = m0 + r; gr = gr < NN ? gr : NN - 1;
            f16x8 o;
            if constexpr (sizeof(AT) == 4) {
                const float4 v0 = *(const float4*)((const float*)A + (size_t)gr * K + k0 + c8);
                const float4 v1 = *(const float4*)((const float*)A + (size_t)gr * K + k0 + c8 + 4);
                o[0] = (_Float16)v0.x; o[1] = (_Float16)v0.y;
                o[2] = (_Float16)v0.z; o[3] = (_Float16)v0.w;
                o[4] = (_Float16)v1.x; o[5] = (_Float16)v1.y;
                o[6] = (_Float16)v1.z; o[7] = (_Float16)v1.w;
            } else {
                // slice-major A: [slice][NN][32]
                const int kk = k0 + c8;
                o = *(const f16x8*)((const _Float16*)A +
                        (size_t)(kk >> 5) * ((size_t)NN * 32) +
                        (size_t)gr * 32 + (kk & 31));
            }
            *(f16x8*)(&As[r][c8]) = o;
        }
#pragma unroll
        for (int p = 0; p < 4; ++p) {
            int r = p * 32 + rr;
            f16x8 v = *(const f16x8*)(Bt + (size_t)(n0 + r) * K + k0 + c8);
            *(f16x8*)(&Bs[r][c8]) = v;
        }
        __syncthreads();
#pragma unroll
        for (int kc = 0; kc < BK; kc += 32) {
            f16x8 af[4], bf[4];
#pragma unroll
            for (int mi = 0; mi < 4; ++mi)
                af[mi] = *(const f16x8*)(&As[wm * 64 + mi * 16 + row_m][kc + quad * 8]);
#pragma unroll
            for (int ni = 0; ni < 4; ++ni)
                bf[ni] = *(const f16x8*)(&Bs[wn * 64 + ni * 16 + row_m][kc + quad * 8]);
            // swapped operands: D holds C^T fragment
#pragma unroll
            for (int mi = 0; mi < 4; ++mi)
#pragma unroll
                for (int ni = 0; ni < 4; ++ni)
                    acc[mi][ni] = __builtin_amdgcn_mfma_f32_16x16x32_f16(
                        bf[ni], af[mi], acc[mi][ni], 0, 0, 0);
        }
        __syncthreads();
    }
    // store C (slice-major): value(lane,reg) of acc[mi][ni] is channel
    //   c = n0 + wn*64 + ni*16 + quad*4 + reg of row m.
#pragma unroll
    for (int mi = 0; mi < 4; ++mi) {
        int m = m0 + wm * 64 + mi * 16 + row_m;
        if (m < NN) {
#pragma unroll
            for (int ni = 0; ni < 4; ++ni) {
                f16x4 o;
                o[0] = (_Float16)acc[mi][ni][0];
                o[1] = (_Float16)acc[mi][ni][1];
                o[2] = (_Float16)acc[mi][ni][2];
                o[3] = (_Float16)acc[mi][ni][3];
                const int c = n0 + wn * 64 + ni * 16 + quad * 4;
                *(f16x4*)(C + (size_t)(c >> 5) * ((size_t)NN * 32) +
                          (size_t)m * 32 + (c & 31)) = o;
            }
        }
    }
    // fused logits: this wave's 64-ch slice == head (2*by + wn)
    const int head = blockIdx.y * 2 + wn;
    const float* attsv = att_s + head * HID;
    const float* attdv = att_d + head * HID;
    float avs[4][4], avd[4][4];
#pragma unroll
    for (int ni = 0; ni < 4; ++ni)
#pragma unroll
        for (int r = 0; r < 4; ++r) {
            avs[ni][r] = attsv[ni * 16 + quad * 4 + r];
            avd[ni][r] = attdv[ni * 16 + quad * 4 + r];
        }
#pragma unroll
    for (int mi = 0; mi < 4; ++mi) {
        float ps = 0.f, pd = 0.f;
#pragma unroll
        for (int ni = 0; ni < 4; ++ni)
#pragma unroll
            for (int r = 0; r < 4; ++r) {
                ps += acc[mi][ni][r] * avs[ni][r];
                pd += acc[mi][ni][r] * avd[ni][r];
            }
        ps += __shfl_xor(ps, 16); ps += __shfl_xor(ps, 32);
        pd += __shfl_xor(pd, 16); pd += __shfl_xor(pd, 32);
        int m = m0 + wm * 64 + mi * 16 + row_m;
        if (quad == 0 && m < NN) {
            a_s[(size_t)head * NN + m] = ps;   // head-major
            a_d[(size_t)head * NN + m] = pd;
        }
    }
}

// ---------------------------------------------------------------------------
// Sliced GAT softmax + aggregation, R3 structure:
//   slice = blockIdx&7 (XCD-pinned, L2-resident h slice: proven in R1).
//   Wave handles 8 dst nodes: group g = lane>>3 owns node n0+g; its 8 lanes
//   hold the node's 32 slice-channels (f16x4/lane). Zero reduction shuffles.
//   Edges processed in BATCHES of 8: one u16x8 load grabs 8 slot ids (same
//   address across the group's 8 lanes -> 1 transaction), next batch's slot
//   load is software-pipelined, inner 8 fully unrolled -> 16 independent
//   gathers in flight per lane. Breaks R2's slot->gather latency chain.
// ---------------------------------------------------------------------------
__global__ __launch_bounds__(256) void k_aggregate(
    const _Float16* __restrict__ h, const float* __restrict__ a_s,
    const float* __restrict__ a_d, const int* __restrict__ cnt,
    const unsigned short* __restrict__ slot, const float* __restrict__ bias,
    _Float16* __restrict__ out, int apply_elu) {
    const int tid = threadIdx.x;
    const int lane = tid & 63;
    const int wv = tid >> 6;              // wave 0..3
    const int slice = blockIdx.x & 7;
    const int head = slice >> 1;
    const int g = lane >> 3;              // node sub-index 0..7
    const int ch = (lane & 7) * 4;        // channel offset within slice

    const int n = (blockIdx.x >> 3) * 32 + wv * 8 + g;
    const bool nvalid = n < NN;
    const int nc = nvalid ? n : NN - 1;

    const _Float16* __restrict__ hs = h + (size_t)slice * ((size_t)NN * 32);
    const float* __restrict__ asv = a_s + (size_t)head * NN;

    const int deg = nvalid ? min(cnt[nc], CAP) : 0;
    const float adn = a_d[(size_t)head * NN + nc];
    // 16B-aligned batched slot view (CAP=96 divisible by 8)
    const u16x8* __restrict__ slv = (const u16x8*)(slot + (size_t)nc * CAP);

    // self-loop seed (each lane: full contribution for its 4 channels)
    const float ws = __expf(leaky(asv[nc] + adn));
    const f16x4 hn = *(const f16x4*)(hs + ((size_t)nc << 5) + ch);
    float l = ws;
    float acc0 = ws * (float)hn[0];
    float acc1 = ws * (float)hn[1];
    float acc2 = ws * (float)hn[2];
    float acc3 = ws * (float)hn[3];

    // wave-max degree across the 8 groups (one-time cost)
    int md = deg;
    md = max(md, __shfl_xor(md, 8));
    md = max(md, __shfl_xor(md, 16));
    md = max(md, __shfl_xor(md, 32));

    const int nb = (md + 7) >> 3;          // batches of 8 edges
    u16x8 sv_next;
    if (nb > 0) sv_next = slv[0];
    for (int b = 0; b < nb; ++b) {
        const u16x8 sv = sv_next;
        if (b + 1 < nb) sv_next = slv[b + 1];   // prefetch next batch's slots
        const int jb = b << 3;
#pragma unroll
        for (int k = 0; k < 8; ++k) {
            const bool act = (jb + k) < deg;
            const int s = act ? (int)sv[k] : nc;   // junk slot -> safe row
            const float w = act ? __expf(leaky(asv[s] + adn)) : 0.f;
            const f16x4 hv = *(const f16x4*)(hs + ((size_t)s << 5) + ch);
            l += w;
            acc0 += w * (float)hv[0];
            acc1 += w * (float)hv[1];
            acc2 += w * (float)hv[2];
            acc3 += w * (float)hv[3];
        }
    }

    const float inv = 1.f / l;
    const float4 bb = *(const float4*)(bias + (slice << 5) + ch);
    float v0 = acc0 * inv + bb.x;
    float v1 = acc1 * inv + bb.y;
    float v2 = acc2 * inv + bb.z;
    float v3 = acc3 * inv + bb.w;
    if (apply_elu) {
        // expf-1 instead of expm1f: output is f16 (ulp 5e-4), error ~1e-7
        v0 = v0 > 0.f ? v0 : __expf(v0) - 1.f;
        v1 = v1 > 0.f ? v1 : __expf(v1) - 1.f;
        v2 = v2 > 0.f ? v2 : __expf(v2) - 1.f;
        v3 = v3 > 0.f ? v3 : __expf(v3) - 1.f;
    }
    if (nvalid) {
        f16x4 o;
        o[0] = (_Float16)v0; o[1] = (_Float16)v1;
        o[2] = (_Float16)v2; o[3] = (_Float16)v3;
        *(f16x4*)(out + (size_t)slice * ((size_t)NN * 32) + ((size_t)n << 5) + ch) = o;
    }
}

// ---------------------------------------------------------------------------
// Fused global mean pool + final FC: one 256-thr block per graph.
// h slice-major: channel c of node n at h[(c>>5)*NN*32 + n*32 + (c&31)].
// ---------------------------------------------------------------------------
__global__ __launch_bounds__(256) void k_pool_fc(const _Float16* __restrict__ h,
                                                 const int* __restrict__ batch,
                                                 const float* __restrict__ fc_w,
                                                 const float* __restrict__ fc_b,
                                                 float* __restrict__ out) {
    __shared__ float row[D1];
    int g = blockIdx.x, c = threadIdx.x;
    int lo = 0, hi = NN;
    while (lo < hi) { int mid = (lo + hi) >> 1; if (batch[mid] < g) lo = mid + 1; else hi = mid; }
    int start = lo;
    hi = NN;
    while (lo < hi) { int mid = (lo + hi) >> 1; if (batch[mid] < g + 1) lo = mid + 1; else hi = mid; }
    int end = lo;

    const _Float16* hsl = h + (size_t)(c >> 5) * ((size_t)NN * 32) + (c & 31);
    float acc = 0.f;
    for (int n = start; n < end; ++n) acc += (float)hsl[(size_t)n << 5];
    float inv = 1.f / fmaxf((float)(end - start), 1.f);
    row[c] = acc * inv;
    __syncthreads();
    if (c < FOUT) {
        float o = 0.f;
#pragma unroll 4
        for (int k = 0; k < D1; ++k) o += row[k] * fc_w[k * FOUT + c];
        out[(size_t)g * FOUT + c] = o + fc_b[c];
    }
}

// ---------------------------------------------------------------------------
extern "C" void kernel_launch(void* const* d_in, const int* in_sizes, int n_in,
                              void* d_out, int out_size, void* d_ws, size_t ws_size,
                              hipStream_t stream) {
    const float* x        = (const float*)d_in[0];
    const int*   ei       = (const int*)d_in[1];
    const int*   batch    = (const int*)d_in[2];
    const float* W1       = (const float*)d_in[3];
    const float* att_src1 = (const float*)d_in[4];
    const float* att_dst1 = (const float*)d_in[5];
    const float* b1       = (const float*)d_in[6];
    const float* W2       = (const float*)d_in[7];
    const float* att_src2 = (const float*)d_in[8];
    const float* att_dst2 = (const float*)d_in[9];
    const float* b2       = (const float*)d_in[10];
    const float* fc_w     = (const float*)d_in[11];
    const float* fc_b     = (const float*)d_in[12];
    float* out = (float*)d_out;

    // workspace carve-up (~63 MB)
    _Float16* h_pre  = (_Float16*)d_ws;                       // NN*D1 f16 (slice-major)
    _Float16* h_act  = h_pre + (size_t)NN * D1;               // NN*D1 f16 (slice-major)
    _Float16* w1t    = h_act + (size_t)NN * D1;               // 256*128
    _Float16* w2t    = w1t + 256 * FIN;                       // 256*256
    float* a_s       = (float*)(w2t + 256 * D1);              // [4][NN] head-major
    float* a_d       = a_s + (size_t)NN * 4;
    int*   cnt       = (int*)(a_d + (size_t)NN * 4);          // NN ints
    unsigned short* slot16 = (unsigned short*)(cnt + NN);     // NN*CAP u16 (9.6 MB)

    const int nblk_edges = (EE + 255) / 256;

    // ---- adjacency build (memset + single scatter; scan-free) ----
    hipMemsetAsync(cnt, 0, NN * sizeof(int), stream);
    k_scatter_direct<<<nblk_edges, 256, 0, stream>>>(ei, cnt, slot16);

    // ---- weight transposes (1 dispatch) ----
    k_cvt_w<<<(256 * (FIN + D1) + 255) / 256, 256, 0, stream>>>(W1, W2, w1t, w2t);

    dim3 ggrid((NN + BM - 1) / BM, D1 / BN);
    const int agg_grid = ((NN + 31) / 32) * 8;   // 32 nodes/block x 8 slices

    // ---- layer 1 (GEMM + fused logits, sliced aggregate) ----
    k_gemm<FIN, float><<<ggrid, 256, 0, stream>>>(x, w1t, h_pre,
                                                  att_src1, att_dst1, a_s, a_d);
    k_aggregate<<<agg_grid, 256, 0, stream>>>(h_pre, a_s, a_d, cnt, slot16, b1, h_act, 1);

    // ---- layer 2 ----
    k_gemm<D1, _Float16><<<ggrid, 256, 0, stream>>>(h_act, w2t, h_pre,
                                                    att_src2, att_dst2, a_s, a_d);
    k_aggregate<<<agg_grid, 256, 0, stream>>>(h_pre, a_s, a_d, cnt, slot16, b2, h_act, 1);

    // ---- fused pool + fc ----
    k_pool_fc<<<NG, 256, 0, stream>>>(h_act, batch, fc_w, fc_b, out);
}

// Round 5
// 393.377 us; speedup vs baseline: 1.4657x; 1.0396x over previous
//
#include <hip/hip_runtime.h>
#include <cstddef>
#include <cstdint>

// Problem constants (fixed by the reference)
#define NN 50000      // nodes
#define EE 800000     // edges (before self loops)
#define FIN 128
#define D1 256        // HEADS*HID
#define HID 64
#define HEADS 4
#define NG 512
#define FOUT 64
#define NEG_SLOPE 0.2f
#define CAP 96        // slots per node; deg ~ Poisson(16), P(deg>96) ~ 1e-40

// h layout is SLICE-MAJOR: h[slice][n][32ch], slice = channel>>5.
// slice k (3.2 MB) fits one XCD's 4 MB L2; aggregate blocks pick
// slice = blockIdx&7 so round-robin XCD dispatch pins slice k to XCD k.
// R1 proved residency (FETCH 216->60 MB). R2: latency-bound serial chain.
// R3: u16x8 slot prefetch -> 100 us, VALU-issue floor 52 us (8x redundant
// weight compute). R4/R5: lane-transposed weight duty (1 exp per EDGE, not
// per lane) + ds_bpermute broadcast; predicated slot prefetch; sv_next
// zero-init (poison-safety for deg-0 groups).

typedef _Float16 f16x8 __attribute__((ext_vector_type(8)));
typedef _Float16 f16x4 __attribute__((ext_vector_type(4)));
typedef float f32x4 __attribute__((ext_vector_type(4)));
typedef unsigned short u16x8 __attribute__((ext_vector_type(8)));

__device__ __forceinline__ float leaky(float x) { return fmaxf(x, NEG_SLOPE * x); }

// ---------------------------------------------------------------------------
// Adjacency build: fixed-capacity slot array, u16 node ids (NN < 65536).
// ---------------------------------------------------------------------------
__global__ void k_scatter_direct(const int* __restrict__ ei, int* __restrict__ cnt,
                                 unsigned short* __restrict__ slot) {
    int i = blockIdx.x * 256 + threadIdx.x;
    if (i < EE) {
        int s = ei[i], d = ei[EE + i];
        int p = atomicAdd(&cnt[d], 1);
        if (p < CAP)
            __builtin_nontemporal_store((unsigned short)s, &slot[(size_t)d * CAP + p]);
    }
}

// ---------------------------------------------------------------------------
// Weight transposes: W[K][256] fp32 -> Wt[256][K] fp16, both layers, 1 kernel
// ---------------------------------------------------------------------------
__global__ void k_cvt_w(const float* __restrict__ W1, const float* __restrict__ W2,
                        _Float16* __restrict__ w1t, _Float16* __restrict__ w2t) {
    int idx = blockIdx.x * 256 + threadIdx.x;
    if (idx < 256 * FIN) {
        int n = idx / FIN, k = idx - n * FIN;
        w1t[idx] = (_Float16)W1[(size_t)k * 256 + n];
    } else if (idx < 256 * FIN + 256 * D1) {
        int j = idx - 256 * FIN;
        int n = j >> 8, k = j & 255;
        w2t[j] = (_Float16)W2[(size_t)k * 256 + n];
    }
}

// ---------------------------------------------------------------------------
// MFMA fp16 GEMM (NT) with FUSED attention logits epilogue.
// C written SLICE-MAJOR [8][NN][32]. Layer-2 A operand is slice-major f16;
// layer-1 A is row-major fp32 (input x). a_s/a_d written HEAD-MAJOR [4][NN].
// ---------------------------------------------------------------------------
#define BM 128
#define BN 128
#define BK 64
#define LDK (BK + 4)

template <int K, typename AT>
__global__ __launch_bounds__(256) void k_gemm(const AT* __restrict__ A,
                                              const _Float16* __restrict__ Bt,
                                              _Float16* __restrict__ C,
                                              const float* __restrict__ att_s,
                                              const float* __restrict__ att_d,
                                              float* __restrict__ a_s,
                                              float* __restrict__ a_d) {
    __shared__ _Float16 As[BM][LDK];
    __shared__ _Float16 Bs[BN][LDK];
    const int tid = threadIdx.x;
    const int lane = tid & 63;
    const int wave = tid >> 6;            // 0..3
    const int wm = wave & 1, wn = wave >> 1;
    const int m0 = blockIdx.x * BM;
    const int n0 = blockIdx.y * BN;
    const int row_m = lane & 15, quad = lane >> 4;

    f32x4 acc[4][4];
#pragma unroll
    for (int mi = 0; mi < 4; ++mi)
#pragma unroll
        for (int ni = 0; ni < 4; ++ni)
#pragma unroll
            for (int r = 0; r < 4; ++r) acc[mi][ni][r] = 0.f;

    const int c8 = (tid & 7) * 8;          // f16 column offset within row
    const int rr = tid >> 3;               // 0..31

    for (int k0 = 0; k0 < K; k0 += BK) {
#pragma unroll
        for (int p = 0; p < 4; ++p) {
            int r = p * 32 + rr;
            int gr = m0 + r; gr = gr < NN ? gr : NN - 1;
            f16x8 o;
            if constexpr (sizeof(AT) == 4) {
                const float4 v0 = *(const float4*)((const float*)A + (size_t)gr * K + k0 + c8);
                const float4 v1 = *(const float4*)((const float*)A + (size_t)gr * K + k0 + c8 + 4);
                o[0] = (_Float16)v0.x; o[1] = (_Float16)v0.y;
                o[2] = (_Float16)v0.z; o[3] = (_Float16)v0.w;
                o[4] = (_Float16)v1.x; o[5] = (_Float16)v1.y;
                o[6] = (_Float16)v1.z; o[7] = (_Float16)v1.w;
            } else {
                // slice-major A: [slice][NN][32]
                const int kk = k0 + c8;
                o = *(const f16x8*)((const _Float16*)A +
                        (size_t)(kk >> 5) * ((size_t)NN * 32) +
                        (size_t)gr * 32 + (kk & 31));
            }
            *(f16x8*)(&As[r][c8]) = o;
        }
#pragma unroll
        for (int p = 0; p < 4; ++p) {
            int r = p * 32 + rr;
            f16x8 v = *(const f16x8*)(Bt + (size_t)(n0 + r) * K + k0 + c8);
            *(f16x8*)(&Bs[r][c8]) = v;
        }
        __syncthreads();
#pragma unroll
        for (int kc = 0; kc < BK; kc += 32) {
            f16x8 af[4], bf[4];
#pragma unroll
            for (int mi = 0; mi < 4; ++mi)
                af[mi] = *(const f16x8*)(&As[wm * 64 + mi * 16 + row_m][kc + quad * 8]);
#pragma unroll
            for (int ni = 0; ni < 4; ++ni)
                bf[ni] = *(const f16x8*)(&Bs[wn * 64 + ni * 16 + row_m][kc + quad * 8]);
            // swapped operands: D holds C^T fragment
#pragma unroll
            for (int mi = 0; mi < 4; ++mi)
#pragma unroll
                for (int ni = 0; ni < 4; ++ni)
                    acc[mi][ni] = __builtin_amdgcn_mfma_f32_16x16x32_f16(
                        bf[ni], af[mi], acc[mi][ni], 0, 0, 0);
        }
        __syncthreads();
    }
    // store C (slice-major): value(lane,reg) of acc[mi][ni] is channel
    //   c = n0 + wn*64 + ni*16 + quad*4 + reg of row m.
#pragma unroll
    for (int mi = 0; mi < 4; ++mi) {
        int m = m0 + wm * 64 + mi * 16 + row_m;
        if (m < NN) {
#pragma unroll
            for (int ni = 0; ni < 4; ++ni) {
                f16x4 o;
                o[0] = (_Float16)acc[mi][ni][0];
                o[1] = (_Float16)acc[mi][ni][1];
                o[2] = (_Float16)acc[mi][ni][2];
                o[3] = (_Float16)acc[mi][ni][3];
                const int c = n0 + wn * 64 + ni * 16 + quad * 4;
                *(f16x4*)(C + (size_t)(c >> 5) * ((size_t)NN * 32) +
                          (size_t)m * 32 + (c & 31)) = o;
            }
        }
    }
    // fused logits: this wave's 64-ch slice == head (2*by + wn)
    const int head = blockIdx.y * 2 + wn;
    const float* attsv = att_s + head * HID;
    const float* attdv = att_d + head * HID;
    float avs[4][4], avd[4][4];
#pragma unroll
    for (int ni = 0; ni < 4; ++ni)
#pragma unroll
        for (int r = 0; r < 4; ++r) {
            avs[ni][r] = attsv[ni * 16 + quad * 4 + r];
            avd[ni][r] = attdv[ni * 16 + quad * 4 + r];
        }
#pragma unroll
    for (int mi = 0; mi < 4; ++mi) {
        float ps = 0.f, pd = 0.f;
#pragma unroll
        for (int ni = 0; ni < 4; ++ni)
#pragma unroll
            for (int r = 0; r < 4; ++r) {
                ps += acc[mi][ni][r] * avs[ni][r];
                pd += acc[mi][ni][r] * avd[ni][r];
            }
        ps += __shfl_xor(ps, 16); ps += __shfl_xor(ps, 32);
        pd += __shfl_xor(pd, 16); pd += __shfl_xor(pd, 32);
        int m = m0 + wm * 64 + mi * 16 + row_m;
        if (quad == 0 && m < NN) {
            a_s[(size_t)head * NN + m] = ps;   // head-major
            a_d[(size_t)head * NN + m] = pd;
        }
    }
}

// ---------------------------------------------------------------------------
// Sliced GAT softmax + aggregation, R4/R5 structure:
//   slice = blockIdx&7 (XCD-pinned, L2-resident h slice: proven in R1).
//   Wave: 8 groups x 8 lanes; group g owns node n0+g, its lanes hold 32 ch.
//   Per 8-edge batch:
//     - WEIGHT DUTY: lane k of the group computes w for edge jb+k ONLY
//       (1 asv gather + 1 exp per EDGE instead of per lane -> kills the 8x
//       redundancy behind R3's 52 us VALU floor).
//     - ds_bpermute broadcast: every lane pulls all 8 weights of its group.
//     - h-gather addresses from the batched u16x8 slot register; s clamped
//       to NN-1 so inactive edges (w=0) read valid rows -> NaN-safe.
//   Slot prefetch predicated on the group's OWN remaining degree; sv_next
//   zero-initialized (deg-0 groups must not read poison).
// ---------------------------------------------------------------------------
__global__ __launch_bounds__(256) void k_aggregate(
    const _Float16* __restrict__ h, const float* __restrict__ a_s,
    const float* __restrict__ a_d, const int* __restrict__ cnt,
    const unsigned short* __restrict__ slot, const float* __restrict__ bias,
    _Float16* __restrict__ out, int apply_elu) {
    const int tid = threadIdx.x;
    const int lane = tid & 63;
    const int wv = tid >> 6;              // wave 0..3
    const int slice = blockIdx.x & 7;
    const int head = slice >> 1;
    const int g = lane >> 3;              // node sub-index 0..7
    const int k8 = lane & 7;              // lane role within group
    const int ch = k8 * 4;                // channel offset within slice

    const int n = (blockIdx.x >> 3) * 32 + wv * 8 + g;
    const bool nvalid = n < NN;
    const int nc = nvalid ? n : NN - 1;

    const _Float16* __restrict__ hs = h + (size_t)slice * ((size_t)NN * 32);
    const float* __restrict__ asv = a_s + (size_t)head * NN;

    const int deg = nvalid ? min(cnt[nc], CAP) : 0;
    const float adn = a_d[(size_t)head * NN + nc];
    const unsigned short* __restrict__ sl16 = slot + (size_t)nc * CAP;
    const u16x8* __restrict__ slv = (const u16x8*)sl16;

    // self-loop seed (each lane: full contribution for its 4 channels)
    const float ws = __expf(leaky(asv[nc] + adn));
    const f16x4 hn = *(const f16x4*)(hs + ((size_t)nc << 5) + ch);
    float l = ws;
    float acc0 = ws * (float)hn[0];
    float acc1 = ws * (float)hn[1];
    float acc2 = ws * (float)hn[2];
    float acc3 = ws * (float)hn[3];

    // wave-max degree across the 8 groups (one-time cost)
    int md = deg;
    md = max(md, __shfl_xor(md, 8));
    md = max(md, __shfl_xor(md, 16));
    md = max(md, __shfl_xor(md, 32));

    const int nb = (md + 7) >> 3;          // wave-uniform batch count
    const int nb_own = (deg + 7) >> 3;     // this group's real batch count
    const int bpbase = (lane & 56) << 2;   // bpermute byte addr of group base

    u16x8 sv_next = (u16x8)0;              // defined value for deg-0 groups
    if (0 < nb_own) sv_next = slv[0];
    for (int b = 0; b < nb; ++b) {
        const u16x8 sv = sv_next;
        if (b + 1 < nb_own) sv_next = slv[b + 1];   // predicated prefetch
        const int jb = b << 3;

        // ---- weight duty: this lane computes w for its group's edge jb+k8
        const int sj = jb + k8;
        const bool act = sj < deg;
        const int sraw = act ? (int)sl16[sj] : 0;
        const int sw = min(sraw, NN - 1);
        const float wown = act ? __expf(leaky(asv[sw] + adn)) : 0.f;
        const int wbits = __float_as_int(wown);

        // ---- broadcast all 8 weights of the group
        float wk[8];
#pragma unroll
        for (int k = 0; k < 8; ++k)
            wk[k] = __int_as_float(
                __builtin_amdgcn_ds_bpermute(bpbase + 4 * k, wbits));

        // ---- 8 gathers + FMA (addresses from the batched slot register)
#pragma unroll
        for (int k = 0; k < 8; ++k) {
            const int s = min((int)sv[k], NN - 1);
            const f16x4 hv = *(const f16x4*)(hs + ((size_t)s << 5) + ch);
            const float w = wk[k];
            l += w;
            acc0 += w * (float)hv[0];
            acc1 += w * (float)hv[1];
            acc2 += w * (float)hv[2];
            acc3 += w * (float)hv[3];
        }
    }

    const float inv = 1.f / l;
    const float4 bb = *(const float4*)(bias + (slice << 5) + ch);
    float v0 = acc0 * inv + bb.x;
    float v1 = acc1 * inv + bb.y;
    float v2 = acc2 * inv + bb.z;
    float v3 = acc3 * inv + bb.w;
    if (apply_elu) {
        // expf-1 instead of expm1f: output is f16 (ulp 5e-4), error ~1e-7
        v0 = v0 > 0.f ? v0 : __expf(v0) - 1.f;
        v1 = v1 > 0.f ? v1 : __expf(v1) - 1.f;
        v2 = v2 > 0.f ? v2 : __expf(v2) - 1.f;
        v3 = v3 > 0.f ? v3 : __expf(v3) - 1.f;
    }
    if (nvalid) {
        f16x4 o;
        o[0] = (_Float16)v0; o[1] = (_Float16)v1;
        o[2] = (_Float16)v2; o[3] = (_Float16)v3;
        *(f16x4*)(out + (size_t)slice * ((size_t)NN * 32) + ((size_t)n << 5) + ch) = o;
    }
}

// ---------------------------------------------------------------------------
// Fused global mean pool + final FC: one 256-thr block per graph.
// h slice-major: channel c of node n at h[(c>>5)*NN*32 + n*32 + (c&31)].
// ---------------------------------------------------------------------------
__global__ __launch_bounds__(256) void k_pool_fc(const _Float16* __restrict__ h,
                                                 const int* __restrict__ batch,
                                                 const float* __restrict__ fc_w,
                                                 const float* __restrict__ fc_b,
                                                 float* __restrict__ out) {
    __shared__ float row[D1];
    int g = blockIdx.x, c = threadIdx.x;
    int lo = 0, hi = NN;
    while (lo < hi) { int mid = (lo + hi) >> 1; if (batch[mid] < g) lo = mid + 1; else hi = mid; }
    int start = lo;
    hi = NN;
    while (lo < hi) { int mid = (lo + hi) >> 1; if (batch[mid] < g + 1) lo = mid + 1; else hi = mid; }
    int end = lo;

    const _Float16* hsl = h + (size_t)(c >> 5) * ((size_t)NN * 32) + (c & 31);
    float acc = 0.f;
    for (int n = start; n < end; ++n) acc += (float)hsl[(size_t)n << 5];
    float inv = 1.f / fmaxf((float)(end - start), 1.f);
    row[c] = acc * inv;
    __syncthreads();
    if (c < FOUT) {
        float o = 0.f;
#pragma unroll 4
        for (int k = 0; k < D1; ++k) o += row[k] * fc_w[k * FOUT + c];
        out[(size_t)g * FOUT + c] = o + fc_b[c];
    }
}

// ---------------------------------------------------------------------------
extern "C" void kernel_launch(void* const* d_in, const int* in_sizes, int n_in,
                              void* d_out, int out_size, void* d_ws, size_t ws_size,
                              hipStream_t stream) {
    const float* x        = (const float*)d_in[0];
    const int*   ei       = (const int*)d_in[1];
    const int*   batch    = (const int*)d_in[2];
    const float* W1       = (const float*)d_in[3];
    const float* att_src1 = (const float*)d_in[4];
    const float* att_dst1 = (const float*)d_in[5];
    const float* b1       = (const float*)d_in[6];
    const float* W2       = (const float*)d_in[7];
    const float* att_src2 = (const float*)d_in[8];
    const float* att_dst2 = (const float*)d_in[9];
    const float* b2       = (const float*)d_in[10];
    const float* fc_w     = (const float*)d_in[11];
    const float* fc_b     = (const float*)d_in[12];
    float* out = (float*)d_out;

    // workspace carve-up (~63 MB)
    _Float16* h_pre  = (_Float16*)d_ws;                       // NN*D1 f16 (slice-major)
    _Float16* h_act  = h_pre + (size_t)NN * D1;               // NN*D1 f16 (slice-major)
    _Float16* w1t    = h_act + (size_t)NN * D1;               // 256*128
    _Float16* w2t    = w1t + 256 * FIN;                       // 256*256
    float* a_s       = (float*)(w2t + 256 * D1);              // [4][NN] head-major
    float* a_d       = a_s + (size_t)NN * 4;
    int*   cnt       = (int*)(a_d + (size_t)NN * 4);          // NN ints
    unsigned short* slot16 = (unsigned short*)(cnt + NN);     // NN*CAP u16 (9.6 MB)

    const int nblk_edges = (EE + 255) / 256;

    // ---- adjacency build (memset + single scatter; scan-free) ----
    hipMemsetAsync(cnt, 0, NN * sizeof(int), stream);
    k_scatter_direct<<<nblk_edges, 256, 0, stream>>>(ei, cnt, slot16);

    // ---- weight transposes (1 dispatch) ----
    k_cvt_w<<<(256 * (FIN + D1) + 255) / 256, 256, 0, stream>>>(W1, W2, w1t, w2t);

    dim3 ggrid((NN + BM - 1) / BM, D1 / BN);
    const int agg_grid = ((NN + 31) / 32) * 8;   // 32 nodes/block x 8 slices

    // ---- layer 1 (GEMM + fused logits, sliced aggregate) ----
    k_gemm<FIN, float><<<ggrid, 256, 0, stream>>>(x, w1t, h_pre,
                                                  att_src1, att_dst1, a_s, a_d);
    k_aggregate<<<agg_grid, 256, 0, stream>>>(h_pre, a_s, a_d, cnt, slot16, b1, h_act, 1);

    // ---- layer 2 ----
    k_gemm<D1, _Float16><<<ggrid, 256, 0, stream>>>(h_act, w2t, h_pre,
                                                    att_src2, att_dst2, a_s, a_d);
    k_aggregate<<<agg_grid, 256, 0, stream>>>(h_pre, a_s, a_d, cnt, slot16, b2, h_act, 1);

    // ---- fused pool + fc ----
    k_pool_fc<<<NG, 256, 0, stream>>>(h_act, batch, fc_w, fc_b, out);
}

// Round 6
// 376.992 us; speedup vs baseline: 1.5295x; 1.0435x over previous
//
#include <hip/hip_runtime.h>
#include <cstddef>
#include <cstdint>

// Problem constants (fixed by the reference)
#define NN 50000      // nodes
#define EE 800000     // edges (before self loops)
#define FIN 128
#define D1 256        // HEADS*HID
#define HID 64
#define HEADS 4
#define NG 512
#define FOUT 64
#define NEG_SLOPE 0.2f
#define CAP 96        // slots per node; deg ~ Poisson(16), P(deg>96) ~ 1e-40

// h layout is SLICE-MAJOR: h[slice][n][32ch], slice = channel>>5.
// slice k (3.2 MB) fits one XCD's 4 MB L2; aggregate blocks pick
// slice = blockIdx&7 so round-robin XCD dispatch pins slice k to XCD k.
// R1 proved residency (FETCH 216->60 MB). R2: latency-bound serial chain.
// R3: slot prefetch -> 100 us (VALU floor 52 us, 8x redundant weights).
// R5: lane-transposed weight duty + bpermute -> VALU floor 35 us, but
// latency-bound again (weight chain unpipelined). R6: depth-2 pipeline of
// the WHOLE weight chain (slot reg -> extract -> asv gather issued one
// batch early); padding gathers read own row (junk slots were random traffic).

typedef _Float16 f16x8 __attribute__((ext_vector_type(8)));
typedef _Float16 f16x4 __attribute__((ext_vector_type(4)));
typedef float f32x4 __attribute__((ext_vector_type(4)));
typedef unsigned short u16x8 __attribute__((ext_vector_type(8)));
typedef unsigned int u32x4 __attribute__((ext_vector_type(4)));

__device__ __forceinline__ float leaky(float x) { return fmaxf(x, NEG_SLOPE * x); }

// extract element idx (0..7, per-lane runtime) from a u16x8 register without
// scratch: static dword selects (3 cndmask) + half select. Rule-#20-safe.
__device__ __forceinline__ int extract_slot(u16x8 v, int idx) {
    u32x4 d = __builtin_bit_cast(u32x4, v);
    unsigned a = (idx & 4) ? d[2] : d[0];
    unsigned b = (idx & 4) ? d[3] : d[1];
    unsigned dw = (idx & 2) ? b : a;
    return (int)((idx & 1) ? (dw >> 16) : (dw & 0xffffu));
}

// ---------------------------------------------------------------------------
// Adjacency build: fixed-capacity slot array, u16 node ids (NN < 65536).
// ---------------------------------------------------------------------------
__global__ void k_scatter_direct(const int* __restrict__ ei, int* __restrict__ cnt,
                                 unsigned short* __restrict__ slot) {
    int i = blockIdx.x * 256 + threadIdx.x;
    if (i < EE) {
        int s = ei[i], d = ei[EE + i];
        int p = atomicAdd(&cnt[d], 1);
        if (p < CAP)
            __builtin_nontemporal_store((unsigned short)s, &slot[(size_t)d * CAP + p]);
    }
}

// ---------------------------------------------------------------------------
// Weight transposes: W[K][256] fp32 -> Wt[256][K] fp16, both layers, 1 kernel
// ---------------------------------------------------------------------------
__global__ void k_cvt_w(const float* __restrict__ W1, const float* __restrict__ W2,
                        _Float16* __restrict__ w1t, _Float16* __restrict__ w2t) {
    int idx = blockIdx.x * 256 + threadIdx.x;
    if (idx < 256 * FIN) {
        int n = idx / FIN, k = idx - n * FIN;
        w1t[idx] = (_Float16)W1[(size_t)k * 256 + n];
    } else if (idx < 256 * FIN + 256 * D1) {
        int j = idx - 256 * FIN;
        int n = j >> 8, k = j & 255;
        w2t[j] = (_Float16)W2[(size_t)k * 256 + n];
    }
}

// ---------------------------------------------------------------------------
// MFMA fp16 GEMM (NT) with FUSED attention logits epilogue.
// C written SLICE-MAJOR [8][NN][32]. Layer-2 A operand is slice-major f16;
// layer-1 A is row-major fp32 (input x). a_s/a_d written HEAD-MAJOR [4][NN].
// ---------------------------------------------------------------------------
#define BM 128
#define BN 128
#define BK 64
#define LDK (BK + 4)

template <int K, typename AT>
__global__ __launch_bounds__(256) void k_gemm(const AT* __restrict__ A,
                                              const _Float16* __restrict__ Bt,
                                              _Float16* __restrict__ C,
                                              const float* __restrict__ att_s,
                                              const float* __restrict__ att_d,
                                              float* __restrict__ a_s,
                                              float* __restrict__ a_d) {
    __shared__ _Float16 As[BM][LDK];
    __shared__ _Float16 Bs[BN][LDK];
    const int tid = threadIdx.x;
    const int lane = tid & 63;
    const int wave = tid >> 6;            // 0..3
    const int wm = wave & 1, wn = wave >> 1;
    const int m0 = blockIdx.x * BM;
    const int n0 = blockIdx.y * BN;
    const int row_m = lane & 15, quad = lane >> 4;

    f32x4 acc[4][4];
#pragma unroll
    for (int mi = 0; mi < 4; ++mi)
#pragma unroll
        for (int ni = 0; ni < 4; ++ni)
#pragma unroll
            for (int r = 0; r < 4; ++r) acc[mi][ni][r] = 0.f;

    const int c8 = (tid & 7) * 8;          // f16 column offset within row
    const int rr = tid >> 3;               // 0..31

    for (int k0 = 0; k0 < K; k0 += BK) {
#pragma unroll
        for (int p = 0; p < 4; ++p) {
            int r = p * 32 + rr;
            int gr = m0 + r; gr = gr < NN ? gr : NN - 1;
            f16x8 o;
            if constexpr (sizeof(AT) == 4) {
                const float4 v0 = *(const float4*)((const float*)A + (size_t)gr * K + k0 + c8);
                const float4 v1 = *(const float4*)((const float*)A + (size_t)gr * K + k0 + c8 + 4);
                o[0] = (_Float16)v0.x; o[1] = (_Float16)v0.y;
                o[2] = (_Float16)v0.z; o[3] = (_Float16)v0.w;
                o[4] = (_Float16)v1.x; o[5] = (_Float16)v1.y;
                o[6] = (_Float16)v1.z; o[7] = (_Float16)v1.w;
            } else {
                // slice-major A: [slice][NN][32]
                const int kk = k0 + c8;
                o = *(const f16x8*)((const _Float16*)A +
                        (size_t)(kk >> 5) * ((size_t)NN * 32) +
                        (size_t)gr * 32 + (kk & 31));
            }
            *(f16x8*)(&As[r][c8]) = o;
        }
#pragma unroll
        for (int p = 0; p < 4; ++p) {
            int r = p * 32 + rr;
            f16x8 v = *(const f16x8*)(Bt + (size_t)(n0 + r) * K + k0 + c8);
            *(f16x8*)(&Bs[r][c8]) = v;
        }
        __syncthreads();
#pragma unroll
        for (int kc = 0; kc < BK; kc += 32) {
            f16x8 af[4], bf[4];
#pragma unroll
            for (int mi = 0; mi < 4; ++mi)
                af[mi] = *(const f16x8*)(&As[wm * 64 + mi * 16 + row_m][kc + quad * 8]);
#pragma unroll
            for (int ni = 0; ni < 4; ++ni)
                bf[ni] = *(const f16x8*)(&Bs[wn * 64 + ni * 16 + row_m][kc + quad * 8]);
            // swapped operands: D holds C^T fragment
#pragma unroll
            for (int mi = 0; mi < 4; ++mi)
#pragma unroll
                for (int ni = 0; ni < 4; ++ni)
                    acc[mi][ni] = __builtin_amdgcn_mfma_f32_16x16x32_f16(
                        bf[ni], af[mi], acc[mi][ni], 0, 0, 0);
        }
        __syncthreads();
    }
    // store C (slice-major): value(lane,reg) of acc[mi][ni] is channel
    //   c = n0 + wn*64 + ni*16 + quad*4 + reg of row m.
#pragma unroll
    for (int mi = 0; mi < 4; ++mi) {
        int m = m0 + wm * 64 + mi * 16 + row_m;
        if (m < NN) {
#pragma unroll
            for (int ni = 0; ni < 4; ++ni) {
                f16x4 o;
                o[0] = (_Float16)acc[mi][ni][0];
                o[1] = (_Float16)acc[mi][ni][1];
                o[2] = (_Float16)acc[mi][ni][2];
                o[3] = (_Float16)acc[mi][ni][3];
                const int c = n0 + wn * 64 + ni * 16 + quad * 4;
                *(f16x4*)(C + (size_t)(c >> 5) * ((size_t)NN * 32) +
                          (size_t)m * 32 + (c & 31)) = o;
            }
        }
    }
    // fused logits: this wave's 64-ch slice == head (2*by + wn)
    const int head = blockIdx.y * 2 + wn;
    const float* attsv = att_s + head * HID;
    const float* attdv = att_d + head * HID;
    float avs[4][4], avd[4][4];
#pragma unroll
    for (int ni = 0; ni < 4; ++ni)
#pragma unroll
        for (int r = 0; r < 4; ++r) {
            avs[ni][r] = attsv[ni * 16 + quad * 4 + r];
            avd[ni][r] = attdv[ni * 16 + quad * 4 + r];
        }
#pragma unroll
    for (int mi = 0; mi < 4; ++mi) {
        float ps = 0.f, pd = 0.f;
#pragma unroll
        for (int ni = 0; ni < 4; ++ni)
#pragma unroll
            for (int r = 0; r < 4; ++r) {
                ps += acc[mi][ni][r] * avs[ni][r];
                pd += acc[mi][ni][r] * avd[ni][r];
            }
        ps += __shfl_xor(ps, 16); ps += __shfl_xor(ps, 32);
        pd += __shfl_xor(pd, 16); pd += __shfl_xor(pd, 32);
        int m = m0 + wm * 64 + mi * 16 + row_m;
        if (quad == 0 && m < NN) {
            a_s[(size_t)head * NN + m] = ps;   // head-major
            a_d[(size_t)head * NN + m] = pd;
        }
    }
}

// ---------------------------------------------------------------------------
// Sliced GAT softmax + aggregation, R6 structure:
//   slice = blockIdx&7 (XCD-pinned, L2-resident h slice: proven in R1).
//   Wave: 8 groups x 8 lanes; group g owns node n0+g, its lanes hold 32 ch.
//   Weight duty (R5): lane k of the group computes w for edge jb+k only;
//   ds_bpermute broadcasts the 8 weights.
//   R6: the weight chain (slot -> extract -> asv gather) is pipelined ONE
//   BATCH AHEAD (depth-2 slot registers): at batch b, asv for b+1 is already
//   in flight; per-batch critical path shrinks to exp -> bpermute -> FMA.
//   Padding edges gather the node's own row nc (L1-hot) instead of junk
//   slot memory (random uninit u16 -> random traffic).
// ---------------------------------------------------------------------------
__global__ __launch_bounds__(256) void k_aggregate(
    const _Float16* __restrict__ h, const float* __restrict__ a_s,
    const float* __restrict__ a_d, const int* __restrict__ cnt,
    const unsigned short* __restrict__ slot, const float* __restrict__ bias,
    _Float16* __restrict__ out, int apply_elu) {
    const int tid = threadIdx.x;
    const int lane = tid & 63;
    const int wv = tid >> 6;              // wave 0..3
    const int slice = blockIdx.x & 7;
    const int head = slice >> 1;
    const int g = lane >> 3;              // node sub-index 0..7
    const int k8 = lane & 7;              // lane role within group
    const int ch = k8 * 4;                // channel offset within slice

    const int n = (blockIdx.x >> 3) * 32 + wv * 8 + g;
    const bool nvalid = n < NN;
    const int nc = nvalid ? n : NN - 1;

    const _Float16* __restrict__ hs = h + (size_t)slice * ((size_t)NN * 32);
    const float* __restrict__ asv = a_s + (size_t)head * NN;

    const int deg = nvalid ? min(cnt[nc], CAP) : 0;
    const float adn = a_d[(size_t)head * NN + nc];
    const unsigned short* __restrict__ sl16 = slot + (size_t)nc * CAP;
    const u16x8* __restrict__ slv = (const u16x8*)sl16;

    // self-loop seed (each lane: full contribution for its 4 channels)
    const float ws = __expf(leaky(asv[nc] + adn));
    const f16x4 hn = *(const f16x4*)(hs + ((size_t)nc << 5) + ch);
    float l = ws;
    float acc0 = ws * (float)hn[0];
    float acc1 = ws * (float)hn[1];
    float acc2 = ws * (float)hn[2];
    float acc3 = ws * (float)hn[3];

    // wave-max degree across the 8 groups (one-time cost)
    int md = deg;
    md = max(md, __shfl_xor(md, 8));
    md = max(md, __shfl_xor(md, 16));
    md = max(md, __shfl_xor(md, 32));

    const int nb = (md + 7) >> 3;          // wave-uniform batch count
    const int nb_own = (deg + 7) >> 3;     // this group's real batch count
    const int bpbase = (lane & 56) << 2;   // bpermute byte addr of group base

    // depth-2 slot pipeline + depth-1 weight-gather pipeline
    u16x8 sv_cur = (u16x8)0, sv_next = (u16x8)0;
    if (0 < nb_own) sv_cur = slv[0];
    if (1 < nb_own) sv_next = slv[1];
    // asv for batch 0 (junk-safe clamp: zero vec -> node 0, valid)
    float av = asv[min(extract_slot(sv_cur, k8), NN - 1)];

    for (int b = 0; b < nb; ++b) {
        const int jb = b << 3;

        // ---- weight for THIS batch from the pipelined asv value
        const bool act = (jb + k8) < deg;
        const float wown = act ? __expf(leaky(av + adn)) : 0.f;

        // ---- issue NEXT batch's weight gather + slot prefetch (depth 2)
        const float av_n = asv[min(extract_slot(sv_next, k8), NN - 1)];
        u16x8 sv_nn = (u16x8)0;
        if (b + 2 < nb_own) sv_nn = slv[b + 2];

        // ---- broadcast the group's 8 weights
        const int wbits = __float_as_int(wown);
        float wk[8];
#pragma unroll
        for (int k = 0; k < 8; ++k)
            wk[k] = __int_as_float(
                __builtin_amdgcn_ds_bpermute(bpbase + 4 * k, wbits));

        // ---- 8 gathers + FMA; padding edges read own row nc (L1-hot, w=0)
#pragma unroll
        for (int k = 0; k < 8; ++k) {
            const int s = (jb + k) < deg ? (int)sv_cur[k] : nc;
            const f16x4 hv = *(const f16x4*)(hs + ((size_t)s << 5) + ch);
            const float w = wk[k];
            l += w;
            acc0 += w * (float)hv[0];
            acc1 += w * (float)hv[1];
            acc2 += w * (float)hv[2];
            acc3 += w * (float)hv[3];
        }

        // rotate pipeline
        sv_cur = sv_next;
        sv_next = sv_nn;
        av = av_n;
    }

    const float inv = 1.f / l;
    const float4 bb = *(const float4*)(bias + (slice << 5) + ch);
    float v0 = acc0 * inv + bb.x;
    float v1 = acc1 * inv + bb.y;
    float v2 = acc2 * inv + bb.z;
    float v3 = acc3 * inv + bb.w;
    if (apply_elu) {
        // expf-1 instead of expm1f: output is f16 (ulp 5e-4), error ~1e-7
        v0 = v0 > 0.f ? v0 : __expf(v0) - 1.f;
        v1 = v1 > 0.f ? v1 : __expf(v1) - 1.f;
        v2 = v2 > 0.f ? v2 : __expf(v2) - 1.f;
        v3 = v3 > 0.f ? v3 : __expf(v3) - 1.f;
    }
    if (nvalid) {
        f16x4 o;
        o[0] = (_Float16)v0; o[1] = (_Float16)v1;
        o[2] = (_Float16)v2; o[3] = (_Float16)v3;
        *(f16x4*)(out + (size_t)slice * ((size_t)NN * 32) + ((size_t)n << 5) + ch) = o;
    }
}

// ---------------------------------------------------------------------------
// Fused global mean pool + final FC: one 256-thr block per graph.
// h slice-major: channel c of node n at h[(c>>5)*NN*32 + n*32 + (c&31)].
// ---------------------------------------------------------------------------
__global__ __launch_bounds__(256) void k_pool_fc(const _Float16* __restrict__ h,
                                                 const int* __restrict__ batch,
                                                 const float* __restrict__ fc_w,
                                                 const float* __restrict__ fc_b,
                                                 float* __restrict__ out) {
    __shared__ float row[D1];
    int g = blockIdx.x, c = threadIdx.x;
    int lo = 0, hi = NN;
    while (lo < hi) { int mid = (lo + hi) >> 1; if (batch[mid] < g) lo = mid + 1; else hi = mid; }
    int start = lo;
    hi = NN;
    while (lo < hi) { int mid = (lo + hi) >> 1; if (batch[mid] < g + 1) lo = mid + 1; else hi = mid; }
    int end = lo;

    const _Float16* hsl = h + (size_t)(c >> 5) * ((size_t)NN * 32) + (c & 31);
    float acc = 0.f;
    for (int n = start; n < end; ++n) acc += (float)hsl[(size_t)n << 5];
    float inv = 1.f / fmaxf((float)(end - start), 1.f);
    row[c] = acc * inv;
    __syncthreads();
    if (c < FOUT) {
        float o = 0.f;
#pragma unroll 4
        for (int k = 0; k < D1; ++k) o += row[k] * fc_w[k * FOUT + c];
        out[(size_t)g * FOUT + c] = o + fc_b[c];
    }
}

// ---------------------------------------------------------------------------
extern "C" void kernel_launch(void* const* d_in, const int* in_sizes, int n_in,
                              void* d_out, int out_size, void* d_ws, size_t ws_size,
                              hipStream_t stream) {
    const float* x        = (const float*)d_in[0];
    const int*   ei       = (const int*)d_in[1];
    const int*   batch    = (const int*)d_in[2];
    const float* W1       = (const float*)d_in[3];
    const float* att_src1 = (const float*)d_in[4];
    const float* att_dst1 = (const float*)d_in[5];
    const float* b1       = (const float*)d_in[6];
    const float* W2       = (const float*)d_in[7];
    const float* att_src2 = (const float*)d_in[8];
    const float* att_dst2 = (const float*)d_in[9];
    const float* b2       = (const float*)d_in[10];
    const float* fc_w     = (const float*)d_in[11];
    const float* fc_b     = (const float*)d_in[12];
    float* out = (float*)d_out;

    // workspace carve-up (~63 MB)
    _Float16* h_pre  = (_Float16*)d_ws;                       // NN*D1 f16 (slice-major)
    _Float16* h_act  = h_pre + (size_t)NN * D1;               // NN*D1 f16 (slice-major)
    _Float16* w1t    = h_act + (size_t)NN * D1;               // 256*128
    _Float16* w2t    = w1t + 256 * FIN;                       // 256*256
    float* a_s       = (float*)(w2t + 256 * D1);              // [4][NN] head-major
    float* a_d       = a_s + (size_t)NN * 4;
    int*   cnt       = (int*)(a_d + (size_t)NN * 4);          // NN ints
    unsigned short* slot16 = (unsigned short*)(cnt + NN);     // NN*CAP u16 (9.6 MB)

    const int nblk_edges = (EE + 255) / 256;

    // ---- adjacency build (memset + single scatter; scan-free) ----
    hipMemsetAsync(cnt, 0, NN * sizeof(int), stream);
    k_scatter_direct<<<nblk_edges, 256, 0, stream>>>(ei, cnt, slot16);

    // ---- weight transposes (1 dispatch) ----
    k_cvt_w<<<(256 * (FIN + D1) + 255) / 256, 256, 0, stream>>>(W1, W2, w1t, w2t);

    dim3 ggrid((NN + BM - 1) / BM, D1 / BN);
    const int agg_grid = ((NN + 31) / 32) * 8;   // 32 nodes/block x 8 slices

    // ---- layer 1 (GEMM + fused logits, sliced aggregate) ----
    k_gemm<FIN, float><<<ggrid, 256, 0, stream>>>(x, w1t, h_pre,
                                                  att_src1, att_dst1, a_s, a_d);
    k_aggregate<<<agg_grid, 256, 0, stream>>>(h_pre, a_s, a_d, cnt, slot16, b1, h_act, 1);

    // ---- layer 2 ----
    k_gemm<D1, _Float16><<<ggrid, 256, 0, stream>>>(h_act, w2t, h_pre,
                                                    att_src2, att_dst2, a_s, a_d);
    k_aggregate<<<agg_grid, 256, 0, stream>>>(h_pre, a_s, a_d, cnt, slot16, b2, h_act, 1);

    // ---- fused pool + fc ----
    k_pool_fc<<<NG, 256, 0, stream>>>(h_act, batch, fc_w, fc_b, out);
}

// Round 7
// 364.108 us; speedup vs baseline: 1.5836x; 1.0354x over previous
//
#include <hip/hip_runtime.h>
#include <cstddef>
#include <cstdint>

// Problem constants (fixed by the reference)
#define NN 50000      // nodes
#define EE 800000     // edges (before self loops)
#define FIN 128
#define D1 256        // HEADS*HID
#define HID 64
#define HEADS 4
#define NG 512
#define FOUT 64
#define NEG_SLOPE 0.2f
#define CAP 96        // slots per node; deg ~ Poisson(16), P(deg>96) ~ 1e-40

// R1-R6 arc (channel-sliced, XCD-pinned aggregation) proved L2 residency
// (FETCH 216->59 MB) but floors at ~83 us/dispatch due to structural 8x
// metadata redundancy (46 us VALU floor vs R0's 26). R0's row-major
// full-row-gather aggregate (64.6 us @ 3.8 TB/s) is the better optimum for
// this degree distribution -> reverted to R0 structure. Carry-over kept:
// u16 slot array (node ids < 65536; halves slot stream).

typedef _Float16 f16x8 __attribute__((ext_vector_type(8)));
typedef _Float16 f16x4 __attribute__((ext_vector_type(4)));
typedef float f32x4 __attribute__((ext_vector_type(4)));

__device__ __forceinline__ float leaky(float x) { return x > 0.f ? x : NEG_SLOPE * x; }

// ---------------------------------------------------------------------------
// Adjacency build, scan-free: fixed-capacity slot array (CAP per node), u16.
// ---------------------------------------------------------------------------
__global__ void k_scatter_direct(const int* __restrict__ ei, int* __restrict__ cnt,
                                 unsigned short* __restrict__ slot) {
    int i = blockIdx.x * 256 + threadIdx.x;
    if (i < EE) {
        int s = ei[i], d = ei[EE + i];
        int p = atomicAdd(&cnt[d], 1);
        if (p < CAP)
            __builtin_nontemporal_store((unsigned short)s, &slot[(size_t)d * CAP + p]);
    }
}

// ---------------------------------------------------------------------------
// Weight transposes: W[K][256] fp32 -> Wt[256][K] fp16, both layers, 1 kernel
// ---------------------------------------------------------------------------
__global__ void k_cvt_w(const float* __restrict__ W1, const float* __restrict__ W2,
                        _Float16* __restrict__ w1t, _Float16* __restrict__ w2t) {
    int idx = blockIdx.x * 256 + threadIdx.x;
    if (idx < 256 * FIN) {
        int n = idx / FIN, k = idx - n * FIN;
        w1t[idx] = (_Float16)W1[(size_t)k * 256 + n];
    } else if (idx < 256 * FIN + 256 * D1) {
        int j = idx - 256 * FIN;
        int n = j >> 8, k = j & 255;
        w2t[j] = (_Float16)W2[(size_t)k * 256 + n];
    }
}

// ---------------------------------------------------------------------------
// MFMA fp16 GEMM (NT) with FUSED attention logits epilogue.
// C[M,256] = A[M,K] * Bt[256,K]^T, fp32 acc, fp16 out (ROW-MAJOR, R0 layout).
// BM=BN=128, BK=64; 4 waves 2x2; swapped-operand MFMA -> lane's 4 acc regs
// contiguous in n. Each wave's 64-ch slice == one head (head = 2*by + wn),
// so a_s/a_d for its 64 rows are computed wave-locally from fp32 acc.
// A is fp32 (layer 1, x) or fp16 (layer 2) via template.
// ---------------------------------------------------------------------------
#define BM 128
#define BN 128
#define BK 64
#define LDK (BK + 4)

template <int K, typename AT>
__global__ __launch_bounds__(256) void k_gemm(const AT* __restrict__ A,
                                              const _Float16* __restrict__ Bt,
                                              _Float16* __restrict__ C,
                                              const float* __restrict__ att_s,
                                              const float* __restrict__ att_d,
                                              float* __restrict__ a_s,
                                              float* __restrict__ a_d) {
    __shared__ _Float16 As[BM][LDK];
    __shared__ _Float16 Bs[BN][LDK];
    const int tid = threadIdx.x;
    const int lane = tid & 63;
    const int wave = tid >> 6;            // 0..3
    const int wm = wave & 1, wn = wave >> 1;
    const int m0 = blockIdx.x * BM;
    const int n0 = blockIdx.y * BN;
    const int row_m = lane & 15, quad = lane >> 4;

    f32x4 acc[4][4];
#pragma unroll
    for (int mi = 0; mi < 4; ++mi)
#pragma unroll
        for (int ni = 0; ni < 4; ++ni)
#pragma unroll
            for (int r = 0; r < 4; ++r) acc[mi][ni][r] = 0.f;

    const int c8 = (tid & 7) * 8;          // f16 column offset within row
    const int rr = tid >> 3;               // 0..31

    for (int k0 = 0; k0 < K; k0 += BK) {
#pragma unroll
        for (int p = 0; p < 4; ++p) {
            int r = p * 32 + rr;
            int gr = m0 + r; gr = gr < NN ? gr : NN - 1;
            f16x8 o;
            if constexpr (sizeof(AT) == 4) {
                const float4 v0 = *(const float4*)((const float*)A + (size_t)gr * K + k0 + c8);
                const float4 v1 = *(const float4*)((const float*)A + (size_t)gr * K + k0 + c8 + 4);
                o[0] = (_Float16)v0.x; o[1] = (_Float16)v0.y;
                o[2] = (_Float16)v0.z; o[3] = (_Float16)v0.w;
                o[4] = (_Float16)v1.x; o[5] = (_Float16)v1.y;
                o[6] = (_Float16)v1.z; o[7] = (_Float16)v1.w;
            } else {
                o = *(const f16x8*)((const _Float16*)A + (size_t)gr * K + k0 + c8);
            }
            *(f16x8*)(&As[r][c8]) = o;
        }
#pragma unroll
        for (int p = 0; p < 4; ++p) {
            int r = p * 32 + rr;
            f16x8 v = *(const f16x8*)(Bt + (size_t)(n0 + r) * K + k0 + c8);
            *(f16x8*)(&Bs[r][c8]) = v;
        }
        __syncthreads();
#pragma unroll
        for (int kc = 0; kc < BK; kc += 32) {
            f16x8 af[4], bf[4];
#pragma unroll
            for (int mi = 0; mi < 4; ++mi)
                af[mi] = *(const f16x8*)(&As[wm * 64 + mi * 16 + row_m][kc + quad * 8]);
#pragma unroll
            for (int ni = 0; ni < 4; ++ni)
                bf[ni] = *(const f16x8*)(&Bs[wn * 64 + ni * 16 + row_m][kc + quad * 8]);
            // swapped operands: D holds C^T fragment
#pragma unroll
            for (int mi = 0; mi < 4; ++mi)
#pragma unroll
                for (int ni = 0; ni < 4; ++ni)
                    acc[mi][ni] = __builtin_amdgcn_mfma_f32_16x16x32_f16(
                        bf[ni], af[mi], acc[mi][ni], 0, 0, 0);
        }
        __syncthreads();
    }
    // store C (row-major): value(lane, reg) of acc[mi][ni] =
    //   C[m0+wm*64+mi*16+row_m][n0+wn*64+ni*16+quad*4+reg]
#pragma unroll
    for (int mi = 0; mi < 4; ++mi) {
        int m = m0 + wm * 64 + mi * 16 + row_m;
        if (m < NN) {
#pragma unroll
            for (int ni = 0; ni < 4; ++ni) {
                f16x4 o;
                o[0] = (_Float16)acc[mi][ni][0];
                o[1] = (_Float16)acc[mi][ni][1];
                o[2] = (_Float16)acc[mi][ni][2];
                o[3] = (_Float16)acc[mi][ni][3];
                *(f16x4*)(C + (size_t)m * D1 + n0 + wn * 64 + ni * 16 + quad * 4) = o;
            }
        }
    }
    // fused logits: this wave's 64 channels == head (2*by + wn); local channel
    // of acc[mi][ni][r] is ni*16 + quad*4 + r.
    const int head = blockIdx.y * 2 + wn;
    const float* attsv = att_s + head * HID;
    const float* attdv = att_d + head * HID;
    float avs[4][4], avd[4][4];
#pragma unroll
    for (int ni = 0; ni < 4; ++ni)
#pragma unroll
        for (int r = 0; r < 4; ++r) {
            avs[ni][r] = attsv[ni * 16 + quad * 4 + r];
            avd[ni][r] = attdv[ni * 16 + quad * 4 + r];
        }
#pragma unroll
    for (int mi = 0; mi < 4; ++mi) {
        float ps = 0.f, pd = 0.f;
#pragma unroll
        for (int ni = 0; ni < 4; ++ni)
#pragma unroll
            for (int r = 0; r < 4; ++r) {
                ps += acc[mi][ni][r] * avs[ni][r];
                pd += acc[mi][ni][r] * avd[ni][r];
            }
        ps += __shfl_xor(ps, 16); ps += __shfl_xor(ps, 32);
        pd += __shfl_xor(pd, 16); pd += __shfl_xor(pd, 32);
        int m = m0 + wm * 64 + mi * 16 + row_m;
        if (quad == 0 && m < NN) {
            a_s[m * 4 + head] = ps;   // node-major [NN][4]
            a_d[m * 4 + head] = pd;
        }
    }
}

// ---------------------------------------------------------------------------
// GAT softmax + aggregation (R0-proven structure): one wave per dst node,
// 64-thr blocks. Self-loop folded in (acc seeded with w_self*h[n]).
// Slot-array adjacency (u16): edges of node n at slot[96n .. 96n+cnt[n]).
// Phase 1: lanes batch-compute exp weights into LDS. Phase 2: WAVE-UNIFORM
// scalar loop — slot[j] wave-uniform load, weight via LDS broadcast, f16x4
// gather; denominator summed per-lane for free.
// ---------------------------------------------------------------------------
__global__ __launch_bounds__(64) void k_aggregate(
    const _Float16* __restrict__ h, const float* __restrict__ a_s,
    const float* __restrict__ a_d, const int* __restrict__ cnt,
    const unsigned short* __restrict__ slot, const float* __restrict__ bias,
    _Float16* __restrict__ out, int apply_elu) {
    const int n = blockIdx.x;
    const int tid = threadIdx.x;              // 0..63
    const int myhead = tid >> 4;
    const int c4 = tid * 4;
    const int start = n * CAP;
    const int deg = cnt[n];
    const int end = start + (deg < CAP ? deg : CAP);

    __shared__ float s_w[64][4];

    const float4 ad = *(const float4*)(a_d + (size_t)n * 4);

    // self-loop seed: w_self per head, acc = w_self * h[n]
    const float4 asn = *(const float4*)(a_s + (size_t)n * 4);
    float w0 = __expf(leaky(asn.x + ad.x));
    float w1 = __expf(leaky(asn.y + ad.y));
    float w2 = __expf(leaky(asn.z + ad.z));
    float w3 = __expf(leaky(asn.w + ad.w));
    const float wself = (myhead == 0) ? w0 : (myhead == 1) ? w1 : (myhead == 2) ? w2 : w3;
    const f16x4 hn = *(const f16x4*)(h + ((size_t)n << 8) + c4);
    float l = wself;
    float4 acc = make_float4(wself * (float)hn[0], wself * (float)hn[1],
                             wself * (float)hn[2], wself * (float)hn[3]);

    for (int base = start; base < end; base += 64) {
        const int len = min(64, end - base);
        if (tid < len) {
            const int s = (int)slot[base + tid];
            const float4 as = *(const float4*)(a_s + (size_t)s * 4);
            s_w[tid][0] = __expf(leaky(as.x + ad.x));
            s_w[tid][1] = __expf(leaky(as.y + ad.y));
            s_w[tid][2] = __expf(leaky(as.z + ad.z));
            s_w[tid][3] = __expf(leaky(as.w + ad.w));
        }
        __syncthreads();
#pragma unroll 4
        for (int jj = 0; jj < len; ++jj) {
            const int s = (int)slot[base + jj];         // wave-uniform
            const float w = s_w[jj][myhead];
            const f16x4 hv = *(const f16x4*)(h + ((size_t)s << 8) + c4);
            l += w;
            acc.x += w * (float)hv[0];
            acc.y += w * (float)hv[1];
            acc.z += w * (float)hv[2];
            acc.w += w * (float)hv[3];
        }
        __syncthreads();
    }
    const float inv = 1.f / l;
    const float4 bb = *(const float4*)(bias + c4);
    float vx = acc.x * inv + bb.x;
    float vy = acc.y * inv + bb.y;
    float vz = acc.z * inv + bb.z;
    float vw = acc.w * inv + bb.w;
    if (apply_elu) {
        vx = vx > 0.f ? vx : expm1f(vx);
        vy = vy > 0.f ? vy : expm1f(vy);
        vz = vz > 0.f ? vz : expm1f(vz);
        vw = vw > 0.f ? vw : expm1f(vw);
    }
    f16x4 o;
    o[0] = (_Float16)vx; o[1] = (_Float16)vy; o[2] = (_Float16)vz; o[3] = (_Float16)vw;
    *(f16x4*)(out + (size_t)n * D1 + c4) = o;
}

// ---------------------------------------------------------------------------
// Fused global mean pool + final FC: one 256-thr block per graph.
// batch is sorted -> binary search node range; channel-per-thread sum;
// then threads 0..63 compute the FC row.
// ---------------------------------------------------------------------------
__global__ __launch_bounds__(256) void k_pool_fc(const _Float16* __restrict__ h,
                                                 const int* __restrict__ batch,
                                                 const float* __restrict__ fc_w,
                                                 const float* __restrict__ fc_b,
                                                 float* __restrict__ out) {
    __shared__ float row[D1];
    int g = blockIdx.x, c = threadIdx.x;
    int lo = 0, hi = NN;
    while (lo < hi) { int mid = (lo + hi) >> 1; if (batch[mid] < g) lo = mid + 1; else hi = mid; }
    int start = lo;
    hi = NN;
    while (lo < hi) { int mid = (lo + hi) >> 1; if (batch[mid] < g + 1) lo = mid + 1; else hi = mid; }
    int end = lo;

    float acc = 0.f;
    for (int n = start; n < end; ++n) acc += (float)h[(size_t)n * D1 + c];
    float inv = 1.f / fmaxf((float)(end - start), 1.f);
    row[c] = acc * inv;
    __syncthreads();
    if (c < FOUT) {
        float o = 0.f;
#pragma unroll 4
        for (int k = 0; k < D1; ++k) o += row[k] * fc_w[k * FOUT + c];
        out[(size_t)g * FOUT + c] = o + fc_b[c];
    }
}

// ---------------------------------------------------------------------------
extern "C" void kernel_launch(void* const* d_in, const int* in_sizes, int n_in,
                              void* d_out, int out_size, void* d_ws, size_t ws_size,
                              hipStream_t stream) {
    const float* x        = (const float*)d_in[0];
    const int*   ei       = (const int*)d_in[1];
    const int*   batch    = (const int*)d_in[2];
    const float* W1       = (const float*)d_in[3];
    const float* att_src1 = (const float*)d_in[4];
    const float* att_dst1 = (const float*)d_in[5];
    const float* b1       = (const float*)d_in[6];
    const float* W2       = (const float*)d_in[7];
    const float* att_src2 = (const float*)d_in[8];
    const float* att_dst2 = (const float*)d_in[9];
    const float* b2       = (const float*)d_in[10];
    const float* fc_w     = (const float*)d_in[11];
    const float* fc_b     = (const float*)d_in[12];
    float* out = (float*)d_out;

    // workspace carve-up (~55 MB)
    _Float16* h_pre  = (_Float16*)d_ws;                       // NN*D1 f16
    _Float16* h_act  = h_pre + (size_t)NN * D1;               // NN*D1 f16
    _Float16* w1t    = h_act + (size_t)NN * D1;               // 256*128
    _Float16* w2t    = w1t + 256 * FIN;                       // 256*256
    float* a_s       = (float*)(w2t + 256 * D1);              // [NN][4] node-major
    float* a_d       = a_s + (size_t)NN * 4;
    int*   cnt       = (int*)(a_d + (size_t)NN * 4);          // NN ints
    unsigned short* slot16 = (unsigned short*)(cnt + NN);     // NN*CAP u16 (9.6 MB)

    const int nblk_edges = (EE + 255) / 256;

    // ---- adjacency build (memset + single scatter; scan-free) ----
    hipMemsetAsync(cnt, 0, NN * sizeof(int), stream);
    k_scatter_direct<<<nblk_edges, 256, 0, stream>>>(ei, cnt, slot16);

    // ---- weight transposes (1 dispatch) ----
    k_cvt_w<<<(256 * (FIN + D1) + 255) / 256, 256, 0, stream>>>(W1, W2, w1t, w2t);

    dim3 ggrid((NN + BM - 1) / BM, D1 / BN);

    // ---- layer 1 (GEMM + fused logits, aggregate) ----
    k_gemm<FIN, float><<<ggrid, 256, 0, stream>>>(x, w1t, h_pre,
                                                  att_src1, att_dst1, a_s, a_d);
    k_aggregate<<<NN, 64, 0, stream>>>(h_pre, a_s, a_d, cnt, slot16, b1, h_act, 1);

    // ---- layer 2 ----
    k_gemm<D1, _Float16><<<ggrid, 256, 0, stream>>>(h_act, w2t, h_pre,
                                                    att_src2, att_dst2, a_s, a_d);
    k_aggregate<<<NN, 64, 0, stream>>>(h_pre, a_s, a_d, cnt, slot16, b2, h_act, 1);

    // ---- fused pool + fc ----
    k_pool_fc<<<NG, 256, 0, stream>>>(h_act, batch, fc_w, fc_b, out);
}